// Round 1
// baseline (793.765 us; speedup 1.0000x reference)
//
#include <hip/hip_runtime.h>
#include <hip/hip_bf16.h>
#include <hip/hip_fp16.h>

// Problem constants
#define TT 16
#define NN 2048          // B*S
#define DD 1024
#define MM 1024
#define HH 8
#define ROWS 32768       // T*N
#define JJ 2048          // 2*M (mi | gi packed)

typedef _Float16 f16x8 __attribute__((ext_vector_type(8)));
typedef float f32x4 __attribute__((ext_vector_type(4)));

__device__ __forceinline__ void gload16(const void* g, void* l) {
    __builtin_amdgcn_global_load_lds((const __attribute__((address_space(1))) void*)g,
                                     (__attribute__((address_space(3))) void*)l, 16, 0, 0);
}

// ---------------- pack fp32 -> f16 hi/lo ----------------
__global__ __launch_bounds__(256) void pack_hilo(const float* __restrict__ in,
                                                 __half* __restrict__ hi,
                                                 __half* __restrict__ lo, long n4) {
    long i = (long)blockIdx.x * 256 + threadIdx.x;
    if (i >= n4) return;
    float4 v = ((const float4*)in)[i];
    __half h0 = __float2half(v.x), h1 = __float2half(v.y);
    __half h2 = __float2half(v.z), h3 = __float2half(v.w);
    __half l0 = __float2half(v.x - __half2float(h0));
    __half l1 = __float2half(v.y - __half2float(h1));
    __half l2 = __float2half(v.z - __half2float(h2));
    __half l3 = __float2half(v.w - __half2float(h3));
    ushort4 H = { __half_as_ushort(h0), __half_as_ushort(h1), __half_as_ushort(h2), __half_as_ushort(h3) };
    ushort4 L = { __half_as_ushort(l0), __half_as_ushort(l1), __half_as_ushort(l2), __half_as_ushort(l3) };
    ((ushort4*)hi)[i] = H;
    ((ushort4*)lo)[i] = L;
}

// ---------------- wq[h][m] = scale * sum_hd q[h,hd]*Wrk[h*128+hd, m] ----------------
__global__ __launch_bounds__(256) void compute_wq(const float* __restrict__ Wrk,
                                                  const float* __restrict__ q,
                                                  float* __restrict__ wq) {
    int m = blockIdx.x * 256 + threadIdx.x;   // 0..1023
    int h = blockIdx.y;                        // 0..7
    const float* qh = q + h * 128;
    const float* wr = Wrk + (size_t)h * 128 * MM + m;
    float acc = 0.f;
    for (int hd = 0; hd < 128; hd++) acc = fmaf(qh[hd], wr[(size_t)hd * MM], acc);
    wq[h * MM + m] = acc * 0.08838834764831845f;   // 1/sqrt(128)
}

// ---------------- f16 split GEMM: C[r][c] = sum_k A[r][k]*B_T[c][k] ----------------
// A row-major [Mrows][K] (hi/lo), B given as [Ncols][K] row-major (hi/lo).
// Tile 128x128, BK=32, 256 threads (4 waves), 16x16x32 MFMA, TERMS in {1,3}.
template<int TERMS>
__global__ __launch_bounds__(256, 2)
void gemm_f16(const __half* __restrict__ Ahi, const __half* __restrict__ Alo,
              const __half* __restrict__ Bhi, const __half* __restrict__ Blo,
              float* __restrict__ C, int K, int ldc)
{
    // LDS: [buf][mat(Ahi,Alo,Bhi,Blo)][group 0..7][lane*8 + j] halfs  = 64 KiB
    __shared__ __align__(16) __half lds[2][4][8][512];
    const int tid  = threadIdx.x;
    const int lane = tid & 63;
    const int wave = tid >> 6;
    const int l15  = lane & 15, l4 = lane >> 4;
    const int rb = blockIdx.x * 128;
    const int cb = blockIdx.y * 128;

    auto stage = [&](int buf, int ks) {
        const int k0 = ks * 32;
        #pragma unroll
        for (int qq = 0; qq < 2; qq++) {
            int g = wave * 2 + qq;
            size_t aoff = (size_t)(rb + g * 16 + l15) * K + (k0 + 8 * l4);
            gload16(Ahi + aoff, &lds[buf][0][g][0]);
            if constexpr (TERMS == 3) gload16(Alo + aoff, &lds[buf][1][g][0]);
            size_t boff = (size_t)(cb + g * 16 + l15) * K + (k0 + 8 * l4);
            gload16(Bhi + boff, &lds[buf][2][g][0]);
            if constexpr (TERMS == 3) gload16(Blo + boff, &lds[buf][3][g][0]);
        }
    };

    const int wave_r = (wave >> 1) * 64;
    const int wave_c = (wave & 1) * 64;
    const int ag0 = wave_r >> 4;   // A group base: 0 or 4
    const int bg0 = wave_c >> 4;   // B group base: 0 or 4

    f32x4 acc[4][4] = {};
    const int nks = K >> 5;
    stage(0, 0);
    int buf = 0;
    for (int ks = 0; ks < nks; ks++) {
        __syncthreads();                       // staging of `buf` done; prev reads done
        if (ks + 1 < nks) stage(buf ^ 1, ks + 1);
        f16x8 ah[4], bh[4], al[4], bl[4];
        #pragma unroll
        for (int i = 0; i < 4; i++) {
            ah[i] = *(const f16x8*)&lds[buf][0][ag0 + i][lane * 8];
            bh[i] = *(const f16x8*)&lds[buf][2][bg0 + i][lane * 8];
            if constexpr (TERMS == 3) {
                al[i] = *(const f16x8*)&lds[buf][1][ag0 + i][lane * 8];
                bl[i] = *(const f16x8*)&lds[buf][3][bg0 + i][lane * 8];
            }
        }
        #pragma unroll
        for (int m = 0; m < 4; m++)
            #pragma unroll
            for (int n = 0; n < 4; n++) {
                acc[m][n] = __builtin_amdgcn_mfma_f32_16x16x32_f16(ah[m], bh[n], acc[m][n], 0, 0, 0);
                if constexpr (TERMS == 3) {
                    acc[m][n] = __builtin_amdgcn_mfma_f32_16x16x32_f16(ah[m], bl[n], acc[m][n], 0, 0, 0);
                    acc[m][n] = __builtin_amdgcn_mfma_f32_16x16x32_f16(al[m], bh[n], acc[m][n], 0, 0, 0);
                }
            }
        buf ^= 1;
    }
    // epilogue: C/D layout (HW-verified): col = lane&15, row = 4*(lane>>4)+reg
    #pragma unroll
    for (int m = 0; m < 4; m++)
        #pragma unroll
        for (int n = 0; n < 4; n++) {
            int r0 = rb + wave_r + m * 16 + l4 * 4;
            int c  = cb + wave_c + n * 16 + l15;
            #pragma unroll
            for (int reg = 0; reg < 4; reg++)
                C[(size_t)(r0 + reg) * ldc + c] = acc[m][n][reg];
        }
}

// ---------------- LIF over T for mem + gate paths ----------------
__global__ __launch_bounds__(256)
void lif_kernel(const float* __restrict__ mi_gi, __half* __restrict__ mv,
                float* __restrict__ gmask, const float* __restrict__ gate_thr)
{
    int idx = blockIdx.x * 256 + threadIdx.x;   // n*1024 + m
    int n = idx >> 10, m = idx & 1023;
    const float* pm = mi_gi + (size_t)n * JJ + m;
    const size_t tstride = (size_t)NN * JJ;
    __half* pv = mv + idx;
    float vm = 0.f, vg = 0.f, cnt = 0.f;
    #pragma unroll
    for (int t = 0; t < TT; t++) {
        float im = pm[(size_t)t * tstride];
        vm = 0.99f * vm + im;
        pv[(size_t)t * (NN * MM)] = __float2half(vm);   // pre-reset trace
        if (vm >= 1.0f) vm -= 1.0f;
        float ig = pm[(size_t)t * tstride + MM];
        vg = 0.9f * vg + ig;
        if (vg >= 1.0f) { vg -= 1.0f; cnt += 1.0f; }
    }
    float gs = cnt * 0.0625f;
    gmask[idx] = 1.0f / (1.0f + expf(-10.0f * (gs - gate_thr[0])));
}

// ---------------- attention scores + softmax + mem_read (one block per n) ----------------
__global__ __launch_bounds__(256)
void attn_memread(const __half* __restrict__ mv, const float* __restrict__ wq,
                  const float* __restrict__ gmask, __half* __restrict__ mem_read)
{
    int n = blockIdx.x;
    __shared__ __align__(16) __half smv[TT][1032];   // padded rows (bank spread)
    __shared__ float sw[HH][TT];
    __shared__ float ssm[HH][TT];
    int tid = threadIdx.x;

    for (int t = 0; t < TT; t++) {
        const ushort4* src = (const ushort4*)(mv + ((size_t)t * NN + n) * MM);
        ((ushort4*)&smv[t][0])[tid] = src[tid];
    }
    __syncthreads();

    if (tid < 128) {
        int h = tid >> 4, t = tid & 15;
        const float* w = wq + h * MM;
        float acc = 0.f;
        for (int m = 0; m < MM; m += 2) {
            float2 v = __half22float2(*(const __half2*)&smv[t][m]);
            acc = fmaf(v.x, w[m], acc);
            acc = fmaf(v.y, w[m + 1], acc);
        }
        sw[h][t] = acc;    // scale folded into wq
    }
    __syncthreads();
    if (tid < 8) {
        int h = tid;
        float mx = -1e30f;
        for (int t = 0; t < TT; t++) mx = fmaxf(mx, sw[h][t]);
        float s = 0.f;
        for (int t = 0; t < TT; t++) { float e = __expf(sw[h][t] - mx); ssm[h][t] = e; s += e; }
        float inv = 1.0f / s;
        for (int t = 0; t < TT; t++) ssm[h][t] *= inv;
    }
    __syncthreads();

    const float* gm = gmask + (size_t)n * MM;
    #pragma unroll
    for (int mm = 0; mm < 4; mm++) {
        int m = tid + mm * 256;
        int h = m >> 7;
        float acc = 0.f;
        #pragma unroll
        for (int t = 0; t < TT; t++) acc = fmaf(__half2float(smv[t][m]), ssm[h][t], acc);
        acc *= gm[m];
        mem_read[(size_t)n * MM + m] = __float2half(acc);
    }
}

// ---------------- LayerNorm + residual broadcast over T (one block per n) ----------------
__global__ __launch_bounds__(256)
void ln_add(const float* __restrict__ mem_out, const float* __restrict__ x,
            const float* __restrict__ gamma, const float* __restrict__ beta,
            const float* __restrict__ mmix, float* __restrict__ out)
{
    int n = blockIdx.x, tid = threadIdx.x;
    int lane = tid & 63, wave = tid >> 6;
    __shared__ float sred[10];
    float4 v = ((const float4*)(mem_out + (size_t)n * DD))[tid];
    float s  = v.x + v.y + v.z + v.w;
    float ss = v.x * v.x + v.y * v.y + v.z * v.z + v.w * v.w;
    #pragma unroll
    for (int o = 32; o > 0; o >>= 1) { s += __shfl_down(s, o, 64); ss += __shfl_down(ss, o, 64); }
    if (lane == 0) { sred[wave * 2] = s; sred[wave * 2 + 1] = ss; }
    __syncthreads();
    if (tid == 0) {
        float S = 0.f, SS = 0.f;
        for (int w = 0; w < 4; w++) { S += sred[w * 2]; SS += sred[w * 2 + 1]; }
        float mu = S * (1.0f / DD);
        float var = SS * (1.0f / DD) - mu * mu;
        sred[8] = mu;
        sred[9] = rsqrtf(var + 1e-5f);
    }
    __syncthreads();
    float mu = sred[8], rs = sred[9];
    float4 g = ((const float4*)gamma)[tid];
    float4 b = ((const float4*)beta)[tid];
    float4 nv;
    nv.x = (v.x - mu) * rs * g.x + b.x;
    nv.y = (v.y - mu) * rs * g.y + b.y;
    nv.z = (v.z - mu) * rs * g.z + b.z;
    nv.w = (v.w - mu) * rs * g.w + b.w;
    float mix = 1.0f / (1.0f + expf(-mmix[0]));
    for (int t = 0; t < TT; t++) {
        size_t off = ((size_t)t * NN + n) * DD;
        float4 xv = ((const float4*)(x + off))[tid];
        float4 o;
        o.x = xv.x + mix * nv.x;
        o.y = xv.y + mix * nv.y;
        o.z = xv.z + mix * nv.z;
        o.w = xv.w + mix * nv.w;
        ((float4*)(out + off))[tid] = o;
    }
}

__global__ void ws_sentinel(float* out) { out[0] = 12345.0f; }

extern "C" void kernel_launch(void* const* d_in, const int* in_sizes, int n_in,
                              void* d_out, int out_size, void* d_ws, size_t ws_size,
                              hipStream_t stream)
{
    const float* x     = (const float*)d_in[0];
    const float* Wto   = (const float*)d_in[1];
    const float* Wg    = (const float*)d_in[2];
    const float* Wrk   = (const float*)d_in[3];
    const float* Wfrom = (const float*)d_in[4];
    const float* q     = (const float*)d_in[5];
    const float* gthr  = (const float*)d_in[6];
    const float* gamma = (const float*)d_in[7];
    const float* beta  = (const float*)d_in[8];
    const float* mmix  = (const float*)d_in[9];
    float* out = (float*)d_out;

    char* w = (char*)d_ws;
    size_t off = 0;
    auto alloc = [&](size_t bytes) -> void* {
        void* p = w + off;
        off += (bytes + 255) & ~(size_t)255;
        return p;
    };
    __half* x_hi   = (__half*)alloc((size_t)ROWS * DD * 2);     // 64 MB
    __half* x_lo   = (__half*)alloc((size_t)ROWS * DD * 2);     // 64 MB
    __half* wc_hi  = (__half*)alloc((size_t)JJ * DD * 2);       // 4 MB
    __half* wc_lo  = (__half*)alloc((size_t)JJ * DD * 2);       // 4 MB
    __half* wf_hi  = (__half*)alloc((size_t)DD * MM * 2);       // 2 MB
    __half* wf_lo  = (__half*)alloc((size_t)DD * MM * 2);       // 2 MB (unused)
    float*  wq     = (float*) alloc((size_t)HH * MM * 4);
    float*  mi_gi  = (float*) alloc((size_t)ROWS * JJ * 4);     // 256 MB
    __half* mv     = (__half*)alloc((size_t)TT * NN * MM * 2);  // 64 MB
    float*  gmask  = (float*) alloc((size_t)NN * MM * 4);       // 8 MB
    __half* m_read = (__half*)alloc((size_t)NN * MM * 2);       // 4 MB
    float*  m_out  = (float*) alloc((size_t)NN * DD * 4);       // 8 MB

    if (off > ws_size) {   // workspace too small: signal distinctly and bail
        ws_sentinel<<<1, 1, 0, stream>>>(out);
        return;
    }

    // 1) packs
    pack_hilo<<<(ROWS * DD / 4 + 255) / 256, 256, 0, stream>>>(x, x_hi, x_lo, ROWS * DD / 4);
    pack_hilo<<<(MM * DD / 4 + 255) / 256, 256, 0, stream>>>(Wto, wc_hi, wc_lo, MM * DD / 4);
    pack_hilo<<<(MM * DD / 4 + 255) / 256, 256, 0, stream>>>(Wg, wc_hi + (size_t)MM * DD, wc_lo + (size_t)MM * DD, MM * DD / 4);
    pack_hilo<<<(DD * MM / 4 + 255) / 256, 256, 0, stream>>>(Wfrom, wf_hi, wf_lo, DD * MM / 4);
    compute_wq<<<dim3(4, 8), 256, 0, stream>>>(Wrk, q, wq);

    // 2) big 3-term f16 GEMM: mi|gi = x @ [W_to;W_gate]^T   (32768 x 2048, K=1024)
    gemm_f16<3><<<dim3(ROWS / 128, JJ / 128), 256, 0, stream>>>(x_hi, x_lo, wc_hi, wc_lo, mi_gi, DD, JJ);

    // 3) LIF scan (mem + gate)
    lif_kernel<<<NN * MM / 256, 256, 0, stream>>>(mi_gi, mv, gmask, gthr);

    // 4) attention scores + softmax + gated mem_read
    attn_memread<<<NN, 256, 0, stream>>>(mv, wq, gmask, m_read);

    // 5) mem_out = mem_read @ W_from^T  (2048 x 1024, K=1024), single-term f16
    gemm_f16<1><<<dim3(NN / 128, DD / 128), 256, 0, stream>>>(m_read, m_read, wf_hi, wf_hi, m_out, MM, DD);

    // 6) LayerNorm + residual broadcast over T
    ln_add<<<NN, 256, 0, stream>>>(m_out, x, gamma, beta, mmix, out);
}

// Round 2
// 786.703 us; speedup vs baseline: 1.0090x; 1.0090x over previous
//
#include <hip/hip_runtime.h>
#include <hip/hip_bf16.h>
#include <hip/hip_fp16.h>

// Problem constants
#define TT 16
#define NN 2048          // B*S
#define DD 1024
#define MM 1024
#define HH 8
#define ROWS 32768       // T*N
#define JJ 2048          // 2*M (mi | gi packed)

typedef _Float16 f16x8 __attribute__((ext_vector_type(8)));
typedef float f32x4 __attribute__((ext_vector_type(4)));

__device__ __forceinline__ void gload16(const void* g, void* l) {
    __builtin_amdgcn_global_load_lds((const __attribute__((address_space(1))) void*)g,
                                     (__attribute__((address_space(3))) void*)l, 16, 0, 0);
}

// ---------------- pack fp32 -> f16 hi/lo ----------------
__global__ __launch_bounds__(256) void pack_hilo(const float* __restrict__ in,
                                                 __half* __restrict__ hi,
                                                 __half* __restrict__ lo, long n4) {
    long i = (long)blockIdx.x * 256 + threadIdx.x;
    if (i >= n4) return;
    float4 v = ((const float4*)in)[i];
    __half h0 = __float2half(v.x), h1 = __float2half(v.y);
    __half h2 = __float2half(v.z), h3 = __float2half(v.w);
    __half l0 = __float2half(v.x - __half2float(h0));
    __half l1 = __float2half(v.y - __half2float(h1));
    __half l2 = __float2half(v.z - __half2float(h2));
    __half l3 = __float2half(v.w - __half2float(h3));
    ushort4 H = { __half_as_ushort(h0), __half_as_ushort(h1), __half_as_ushort(h2), __half_as_ushort(h3) };
    ushort4 L = { __half_as_ushort(l0), __half_as_ushort(l1), __half_as_ushort(l2), __half_as_ushort(l3) };
    ((ushort4*)hi)[i] = H;
    ((ushort4*)lo)[i] = L;
}

// ---------------- wq[h][m] = scale * sum_hd q[h,hd]*Wrk[h*128+hd, m] ----------------
__global__ __launch_bounds__(256) void compute_wq(const float* __restrict__ Wrk,
                                                  const float* __restrict__ q,
                                                  float* __restrict__ wq) {
    int m = blockIdx.x * 256 + threadIdx.x;   // 0..1023
    int h = blockIdx.y;                        // 0..7
    const float* qh = q + h * 128;
    const float* wr = Wrk + (size_t)h * 128 * MM + m;
    float acc = 0.f;
    for (int hd = 0; hd < 128; hd++) acc = fmaf(qh[hd], wr[(size_t)hd * MM], acc);
    wq[h * MM + m] = acc * 0.08838834764831845f;   // 1/sqrt(128)
}

// ---------------- f16 split GEMM: C[r][c] = sum_k A[r][k]*B_T[c][k] ----------------
// A row-major [Mrows][K] (hi/lo), B given as [Ncols][K] row-major (hi/lo).
// Tile 128x128, BK=32, 256 threads (4 waves), 16x16x32 MFMA, TERMS in {1,3}.
// 1-D grid, column-fastest ordering (A-panel reuse in L2) + bijective XCD swizzle.
template<int TERMS>
__global__ __launch_bounds__(256, 2)
void gemm_f16(const __half* __restrict__ Ahi, const __half* __restrict__ Alo,
              const __half* __restrict__ Bhi, const __half* __restrict__ Blo,
              float* __restrict__ C, int K, int ldc, int ncb_log2)
{
    // LDS: [buf][mat(Ahi,Alo,Bhi,Blo)][group 0..7][lane*8 + j] halfs  = 64 KiB
    __shared__ __align__(16) __half lds[2][4][8][512];
    const int tid  = threadIdx.x;
    const int lane = tid & 63;
    const int wave = tid >> 6;
    const int l15  = lane & 15, l4 = lane >> 4;

    // XCD-aware bijective swizzle (gridDim.x divisible by 8), then
    // column-fastest tile order: consecutive wg share the same A row-panel.
    const int nwg  = gridDim.x;
    const int orig = blockIdx.x;
    const int wg   = (orig & 7) * (nwg >> 3) + (orig >> 3);
    const int rb = (wg >> ncb_log2) * 128;
    const int cb = (wg & ((1 << ncb_log2) - 1)) * 128;

    auto stage = [&](int buf, int ks) {
        const int k0 = ks * 32;
        #pragma unroll
        for (int qq = 0; qq < 2; qq++) {
            int g = wave * 2 + qq;
            size_t aoff = (size_t)(rb + g * 16 + l15) * K + (k0 + 8 * l4);
            gload16(Ahi + aoff, &lds[buf][0][g][0]);
            if constexpr (TERMS == 3) gload16(Alo + aoff, &lds[buf][1][g][0]);
            size_t boff = (size_t)(cb + g * 16 + l15) * K + (k0 + 8 * l4);
            gload16(Bhi + boff, &lds[buf][2][g][0]);
            if constexpr (TERMS == 3) gload16(Blo + boff, &lds[buf][3][g][0]);
        }
    };

    const int wave_r = (wave >> 1) * 64;
    const int wave_c = (wave & 1) * 64;
    const int ag0 = wave_r >> 4;   // A group base: 0 or 4
    const int bg0 = wave_c >> 4;   // B group base: 0 or 4

    f32x4 acc[4][4] = {};
    const int nks = K >> 5;
    stage(0, 0);
    int buf = 0;
    for (int ks = 0; ks < nks; ks++) {
        __syncthreads();                       // staging of `buf` done; prev reads done
        if (ks + 1 < nks) stage(buf ^ 1, ks + 1);
        f16x8 ah[4], bh[4], al[4], bl[4];
        #pragma unroll
        for (int i = 0; i < 4; i++) {
            ah[i] = *(const f16x8*)&lds[buf][0][ag0 + i][lane * 8];
            bh[i] = *(const f16x8*)&lds[buf][2][bg0 + i][lane * 8];
            if constexpr (TERMS == 3) {
                al[i] = *(const f16x8*)&lds[buf][1][ag0 + i][lane * 8];
                bl[i] = *(const f16x8*)&lds[buf][3][bg0 + i][lane * 8];
            }
        }
        #pragma unroll
        for (int m = 0; m < 4; m++)
            #pragma unroll
            for (int n = 0; n < 4; n++) {
                acc[m][n] = __builtin_amdgcn_mfma_f32_16x16x32_f16(ah[m], bh[n], acc[m][n], 0, 0, 0);
                if constexpr (TERMS == 3) {
                    acc[m][n] = __builtin_amdgcn_mfma_f32_16x16x32_f16(ah[m], bl[n], acc[m][n], 0, 0, 0);
                    acc[m][n] = __builtin_amdgcn_mfma_f32_16x16x32_f16(al[m], bh[n], acc[m][n], 0, 0, 0);
                }
            }
        buf ^= 1;
    }
    // epilogue: C/D layout (HW-verified): col = lane&15, row = 4*(lane>>4)+reg
    #pragma unroll
    for (int m = 0; m < 4; m++)
        #pragma unroll
        for (int n = 0; n < 4; n++) {
            int r0 = rb + wave_r + m * 16 + l4 * 4;
            int c  = cb + wave_c + n * 16 + l15;
            #pragma unroll
            for (int reg = 0; reg < 4; reg++)
                C[(size_t)(r0 + reg) * ldc + c] = acc[m][n][reg];
        }
}

// ---------------- LIF over T for mem + gate paths ----------------
__global__ __launch_bounds__(256)
void lif_kernel(const float* __restrict__ mi_gi, __half* __restrict__ mv,
                float* __restrict__ gmask, const float* __restrict__ gate_thr)
{
    int idx = blockIdx.x * 256 + threadIdx.x;   // n*1024 + m
    int n = idx >> 10, m = idx & 1023;
    const float* pm = mi_gi + (size_t)n * JJ + m;
    const size_t tstride = (size_t)NN * JJ;
    __half* pv = mv + idx;
    float vm = 0.f, vg = 0.f, cnt = 0.f;
    #pragma unroll
    for (int t = 0; t < TT; t++) {
        float im = pm[(size_t)t * tstride];
        vm = 0.99f * vm + im;
        pv[(size_t)t * (NN * MM)] = __float2half(vm);   // pre-reset trace
        if (vm >= 1.0f) vm -= 1.0f;
        float ig = pm[(size_t)t * tstride + MM];
        vg = 0.9f * vg + ig;
        if (vg >= 1.0f) { vg -= 1.0f; cnt += 1.0f; }
    }
    float gs = cnt * 0.0625f;
    gmask[idx] = 1.0f / (1.0f + expf(-10.0f * (gs - gate_thr[0])));
}

// ---------------- attention scores + softmax + mem_read (one block per n) ----------------
__global__ __launch_bounds__(256)
void attn_memread(const __half* __restrict__ mv, const float* __restrict__ wq,
                  const float* __restrict__ gmask, __half* __restrict__ mem_read)
{
    int n = blockIdx.x;
    __shared__ __align__(16) __half smv[TT][1032];   // padded rows (bank spread)
    __shared__ float sw[HH][TT];
    __shared__ float ssm[HH][TT];
    int tid = threadIdx.x;

    for (int t = 0; t < TT; t++) {
        const ushort4* src = (const ushort4*)(mv + ((size_t)t * NN + n) * MM);
        ((ushort4*)&smv[t][0])[tid] = src[tid];
    }
    __syncthreads();

    if (tid < 128) {
        int h = tid >> 4, t = tid & 15;
        const float* w = wq + h * MM;
        float acc = 0.f;
        for (int m = 0; m < MM; m += 2) {
            float2 v = __half22float2(*(const __half2*)&smv[t][m]);
            acc = fmaf(v.x, w[m], acc);
            acc = fmaf(v.y, w[m + 1], acc);
        }
        sw[h][t] = acc;    // scale folded into wq
    }
    __syncthreads();
    if (tid < 8) {
        int h = tid;
        float mx = -1e30f;
        for (int t = 0; t < TT; t++) mx = fmaxf(mx, sw[h][t]);
        float s = 0.f;
        for (int t = 0; t < TT; t++) { float e = __expf(sw[h][t] - mx); ssm[h][t] = e; s += e; }
        float inv = 1.0f / s;
        for (int t = 0; t < TT; t++) ssm[h][t] *= inv;
    }
    __syncthreads();

    const float* gm = gmask + (size_t)n * MM;
    #pragma unroll
    for (int mm = 0; mm < 4; mm++) {
        int m = tid + mm * 256;
        int h = m >> 7;
        float acc = 0.f;
        #pragma unroll
        for (int t = 0; t < TT; t++) acc = fmaf(__half2float(smv[t][m]), ssm[h][t], acc);
        acc *= gm[m];
        mem_read[(size_t)n * MM + m] = __float2half(acc);
    }
}

// ---------------- LayerNorm + residual broadcast over T (one block per n) ----------------
__global__ __launch_bounds__(256)
void ln_add(const float* __restrict__ mem_out, const float* __restrict__ x,
            const float* __restrict__ gamma, const float* __restrict__ beta,
            const float* __restrict__ mmix, float* __restrict__ out)
{
    int n = blockIdx.x, tid = threadIdx.x;
    int lane = tid & 63, wave = tid >> 6;
    __shared__ float sred[10];
    float4 v = ((const float4*)(mem_out + (size_t)n * DD))[tid];
    float s  = v.x + v.y + v.z + v.w;
    float ss = v.x * v.x + v.y * v.y + v.z * v.z + v.w * v.w;
    #pragma unroll
    for (int o = 32; o > 0; o >>= 1) { s += __shfl_down(s, o, 64); ss += __shfl_down(ss, o, 64); }
    if (lane == 0) { sred[wave * 2] = s; sred[wave * 2 + 1] = ss; }
    __syncthreads();
    if (tid == 0) {
        float S = 0.f, SS = 0.f;
        for (int w = 0; w < 4; w++) { S += sred[w * 2]; SS += sred[w * 2 + 1]; }
        float mu = S * (1.0f / DD);
        float var = SS * (1.0f / DD) - mu * mu;
        sred[8] = mu;
        sred[9] = rsqrtf(var + 1e-5f);
    }
    __syncthreads();
    float mu = sred[8], rs = sred[9];
    float4 g = ((const float4*)gamma)[tid];
    float4 b = ((const float4*)beta)[tid];
    float4 nv;
    nv.x = (v.x - mu) * rs * g.x + b.x;
    nv.y = (v.y - mu) * rs * g.y + b.y;
    nv.z = (v.z - mu) * rs * g.z + b.z;
    nv.w = (v.w - mu) * rs * g.w + b.w;
    float mix = 1.0f / (1.0f + expf(-mmix[0]));
    for (int t = 0; t < TT; t++) {
        size_t off = ((size_t)t * NN + n) * DD;
        float4 xv = ((const float4*)(x + off))[tid];
        float4 o;
        o.x = xv.x + mix * nv.x;
        o.y = xv.y + mix * nv.y;
        o.z = xv.z + mix * nv.z;
        o.w = xv.w + mix * nv.w;
        ((float4*)(out + off))[tid] = o;
    }
}

__global__ void ws_sentinel(float* out) { out[0] = 12345.0f; }

extern "C" void kernel_launch(void* const* d_in, const int* in_sizes, int n_in,
                              void* d_out, int out_size, void* d_ws, size_t ws_size,
                              hipStream_t stream)
{
    const float* x     = (const float*)d_in[0];
    const float* Wto   = (const float*)d_in[1];
    const float* Wg    = (const float*)d_in[2];
    const float* Wrk   = (const float*)d_in[3];
    const float* Wfrom = (const float*)d_in[4];
    const float* q     = (const float*)d_in[5];
    const float* gthr  = (const float*)d_in[6];
    const float* gamma = (const float*)d_in[7];
    const float* beta  = (const float*)d_in[8];
    const float* mmix  = (const float*)d_in[9];
    float* out = (float*)d_out;

    char* w = (char*)d_ws;
    size_t off = 0;
    auto alloc = [&](size_t bytes) -> void* {
        void* p = w + off;
        off += (bytes + 255) & ~(size_t)255;
        return p;
    };
    __half* x_hi   = (__half*)alloc((size_t)ROWS * DD * 2);     // 64 MB
    __half* x_lo   = (__half*)alloc((size_t)ROWS * DD * 2);     // 64 MB
    __half* wc_hi  = (__half*)alloc((size_t)JJ * DD * 2);       // 4 MB
    __half* wc_lo  = (__half*)alloc((size_t)JJ * DD * 2);       // 4 MB
    __half* wf_hi  = (__half*)alloc((size_t)DD * MM * 2);       // 2 MB
    __half* wf_lo  = (__half*)alloc((size_t)DD * MM * 2);       // 2 MB (unused)
    float*  wq     = (float*) alloc((size_t)HH * MM * 4);
    float*  mi_gi  = (float*) alloc((size_t)ROWS * JJ * 4);     // 256 MB
    __half* mv     = (__half*)alloc((size_t)TT * NN * MM * 2);  // 64 MB
    float*  gmask  = (float*) alloc((size_t)NN * MM * 4);       // 8 MB
    __half* m_read = (__half*)alloc((size_t)NN * MM * 2);       // 4 MB
    float*  m_out  = (float*) alloc((size_t)NN * DD * 4);       // 8 MB

    if (off > ws_size) {   // workspace too small: signal distinctly and bail
        ws_sentinel<<<1, 1, 0, stream>>>(out);
        return;
    }

    // 1) packs
    pack_hilo<<<(ROWS * DD / 4 + 255) / 256, 256, 0, stream>>>(x, x_hi, x_lo, ROWS * DD / 4);
    pack_hilo<<<(MM * DD / 4 + 255) / 256, 256, 0, stream>>>(Wto, wc_hi, wc_lo, MM * DD / 4);
    pack_hilo<<<(MM * DD / 4 + 255) / 256, 256, 0, stream>>>(Wg, wc_hi + (size_t)MM * DD, wc_lo + (size_t)MM * DD, MM * DD / 4);
    pack_hilo<<<(DD * MM / 4 + 255) / 256, 256, 0, stream>>>(Wfrom, wf_hi, wf_lo, DD * MM / 4);
    compute_wq<<<dim3(4, 8), 256, 0, stream>>>(Wrk, q, wq);

    // 2) big 3-term f16 GEMM: mi|gi = x @ [W_to;W_gate]^T   (32768 x 2048, K=1024)
    //    1-D grid 4096 blocks, col-fastest (ncb=16 -> log2=4), XCD swizzle inside.
    gemm_f16<3><<<(ROWS / 128) * (JJ / 128), 256, 0, stream>>>(x_hi, x_lo, wc_hi, wc_lo, mi_gi, DD, JJ, 4);

    // 3) LIF scan (mem + gate)
    lif_kernel<<<NN * MM / 256, 256, 0, stream>>>(mi_gi, mv, gmask, gthr);

    // 4) attention scores + softmax + gated mem_read
    attn_memread<<<NN, 256, 0, stream>>>(mv, wq, gmask, m_read);

    // 5) mem_out = mem_read @ W_from^T  (2048 x 1024, K=1024), single-term f16
    gemm_f16<1><<<(NN / 128) * (DD / 128), 256, 0, stream>>>(m_read, m_read, wf_hi, wf_hi, m_out, MM, DD, 3);

    // 6) LayerNorm + residual broadcast over T
    ln_add<<<NN, 256, 0, stream>>>(m_out, x, gamma, beta, mmix, out);
}

// Round 3
// 650.791 us; speedup vs baseline: 1.2197x; 1.2088x over previous
//
#include <hip/hip_runtime.h>
#include <hip/hip_bf16.h>
#include <hip/hip_fp16.h>

// Problem constants
#define TT 16
#define NN 2048          // B*S
#define DD 1024
#define MM 1024
#define HH 8
#define ROWS 32768       // T*N
#define JJ 2048          // 2*M (mi | gi packed)

typedef _Float16 f16x8 __attribute__((ext_vector_type(8)));
typedef float f32x4 __attribute__((ext_vector_type(4)));

__device__ __forceinline__ void gload16(const void* g, void* l) {
    __builtin_amdgcn_global_load_lds((const __attribute__((address_space(1))) void*)g,
                                     (__attribute__((address_space(3))) void*)l, 16, 0, 0);
}

// ---------------- pack fp32 -> f16 hi/lo ----------------
__global__ __launch_bounds__(256) void pack_hilo(const float* __restrict__ in,
                                                 __half* __restrict__ hi,
                                                 __half* __restrict__ lo, long n4) {
    long i = (long)blockIdx.x * 256 + threadIdx.x;
    if (i >= n4) return;
    float4 v = ((const float4*)in)[i];
    __half h0 = __float2half(v.x), h1 = __float2half(v.y);
    __half h2 = __float2half(v.z), h3 = __float2half(v.w);
    __half l0 = __float2half(v.x - __half2float(h0));
    __half l1 = __float2half(v.y - __half2float(h1));
    __half l2 = __float2half(v.z - __half2float(h2));
    __half l3 = __float2half(v.w - __half2float(h3));
    ushort4 H = { __half_as_ushort(h0), __half_as_ushort(h1), __half_as_ushort(h2), __half_as_ushort(h3) };
    ushort4 L = { __half_as_ushort(l0), __half_as_ushort(l1), __half_as_ushort(l2), __half_as_ushort(l3) };
    ((ushort4*)hi)[i] = H;
    ((ushort4*)lo)[i] = L;
}

// ---------------- wq[h][m] = scale * sum_hd q[h,hd]*Wrk[h*128+hd, m] ----------------
__global__ __launch_bounds__(256) void compute_wq(const float* __restrict__ Wrk,
                                                  const float* __restrict__ q,
                                                  float* __restrict__ wq) {
    int m = blockIdx.x * 256 + threadIdx.x;   // 0..1023
    int h = blockIdx.y;                        // 0..7
    const float* qh = q + h * 128;
    const float* wr = Wrk + (size_t)h * 128 * MM + m;
    float acc = 0.f;
    for (int hd = 0; hd < 128; hd++) acc = fmaf(qh[hd], wr[(size_t)hd * MM], acc);
    wq[h * MM + m] = acc * 0.08838834764831845f;   // 1/sqrt(128)
}

// =============================================================================
// 256x256 8-phase f16 GEMM (T2+T3+T4+T5), virtual K'=3072 for the 3-term
// hi/lo split: kt<16: Ahi*Bhi, kt<32: Alo*Bhi, else Ahi*Blo.
// 512 threads (8 waves, 2Mx4N), BK=64, 128 KiB LDS (dyn), counted vmcnt(6).
// =============================================================================
__global__ __launch_bounds__(512, 2)
void gemm8p(const __half* __restrict__ Ahi, const __half* __restrict__ Alo,
            const __half* __restrict__ Bhi, const __half* __restrict__ Blo,
            float* __restrict__ C)
{
    extern __shared__ __align__(16) char smem[];
    char* Ab = smem;             // [2 parity][256 rows][64 f16] = 65536 B
    char* Bb = smem + 65536;

    const int tid  = threadIdx.x;
    const int lane = tid & 63;
    const int wave = tid >> 6;
    const int l15  = lane & 15, l4 = lane >> 4;
    const int wm = wave >> 2, wn = wave & 3;

    // 1-D grid 1024 blocks: XCD-contiguous chunks, col-fastest within chunk.
    const int orig = blockIdx.x;
    const int wg   = (orig & 7) * 128 + (orig >> 3);
    const int rb   = (wg >> 3) * 256;
    const int cb   = (wg & 7) * 256;

    auto srcsel = [&](int kt, const __half*& As, const __half*& Bs, int& k0) {
        if (kt < 16)      { As = Ahi; Bs = Bhi; k0 = kt << 6; }
        else if (kt < 32) { As = Alo; Bs = Bhi; k0 = (kt - 16) << 6; }
        else              { As = Ahi; Bs = Blo; k0 = (kt - 32) << 6; }
    };

    // Stage one 16KB half-tile (128 rows x 128B). Linear LDS dest (wave-uniform
    // base + lane*16), inverse-swizzled global source (rule #21).
    auto stage = [&](int mat, int parity, int half, int kt) {
        const __half *As, *Bs; int k0;
        srcsel(kt, As, Bs, k0);
        const __half* src = mat ? Bs : As;
        const int row0    = mat ? cb : rb;
        char* base = (mat ? Bb : Ab) + parity * 32768 + half * 16384;
        #pragma unroll
        for (int j = 0; j < 2; j++) {
            int seg  = j * 8 + wave;                       // 1KB segment
            int row  = half * 128 + seg * 8 + (lane >> 3); // tile row
            int srcb = ((lane & 7) * 16) ^ ((row & 7) << 4);
            const char* g = (const char*)(src + (size_t)(row0 + row) * 1024 + k0) + srcb;
            gload16(g, base + seg * 1024);
        }
    };

    auto rdA = [&](int parity, int row, int ks) -> f16x8 {
        int pb = (ks * 64 + l4 * 16) ^ ((row & 7) << 4);
        return *(const f16x8*)(Ab + parity * 32768 + row * 128 + pb);
    };
    auto rdB = [&](int parity, int row, int ks) -> f16x8 {
        int pb = (ks * 64 + l4 * 16) ^ ((row & 7) << 4);
        return *(const f16x8*)(Bb + parity * 32768 + row * 128 + pb);
    };

    f32x4 acc[8][4] = {};
    const int NKT = 48;

    // Prologue: k0 all 4 halves, then A0,B0,B1 of k1 (A1(k1) staged in ph1 of kt=0).
    stage(0, 0, 0, 0); stage(0, 0, 1, 0); stage(1, 0, 0, 0); stage(1, 0, 1, 0);
    stage(0, 1, 0, 1); stage(1, 1, 0, 1); stage(1, 1, 1, 1);
    asm volatile("s_waitcnt vmcnt(6)" ::: "memory");   // k0 confirmed
    __builtin_amdgcn_sched_barrier(0);
    __builtin_amdgcn_s_barrier();

    for (int kt = 0; kt < NKT; kt++) {
        const int p = kt & 1;
        f16x8 a0[4][2], a1[4][2], bf[4][2];

        // ---- phase 1: read A-qm0 (8) + B-all (8); stage A1(kt+1); MFMA q(0,0)
        #pragma unroll
        for (int i = 0; i < 4; i++)
            #pragma unroll
            for (int ks = 0; ks < 2; ks++) {
                a0[i][ks] = rdA(p, wm * 128 + i * 16 + l15, ks);
                bf[i][ks] = rdB(p, wn * 64  + i * 16 + l15, ks);
            }
        if (kt + 1 < NKT) stage(0, (kt + 1) & 1, 1, kt + 1);
        __builtin_amdgcn_sched_barrier(0);
        __builtin_amdgcn_s_barrier();
        __builtin_amdgcn_s_setprio(1);
        #pragma unroll
        for (int i = 0; i < 4; i++)
            #pragma unroll
            for (int nf = 0; nf < 2; nf++) {
                acc[i][nf] = __builtin_amdgcn_mfma_f32_16x16x32_f16(a0[i][0], bf[nf][0], acc[i][nf], 0, 0, 0);
                acc[i][nf] = __builtin_amdgcn_mfma_f32_16x16x32_f16(a0[i][1], bf[nf][1], acc[i][nf], 0, 0, 0);
            }
        __builtin_amdgcn_s_setprio(0);
        __builtin_amdgcn_sched_barrier(0);
        __builtin_amdgcn_s_barrier();

        // ---- phase 2: stage B0(kt+2); MFMA q(0,1)
        if (kt + 2 < NKT) stage(1, p, 0, kt + 2);
        __builtin_amdgcn_sched_barrier(0);
        __builtin_amdgcn_s_barrier();
        __builtin_amdgcn_s_setprio(1);
        #pragma unroll
        for (int i = 0; i < 4; i++)
            #pragma unroll
            for (int nf = 2; nf < 4; nf++) {
                acc[i][nf] = __builtin_amdgcn_mfma_f32_16x16x32_f16(a0[i][0], bf[nf][0], acc[i][nf], 0, 0, 0);
                acc[i][nf] = __builtin_amdgcn_mfma_f32_16x16x32_f16(a0[i][1], bf[nf][1], acc[i][nf], 0, 0, 0);
            }
        __builtin_amdgcn_s_setprio(0);
        __builtin_amdgcn_sched_barrier(0);
        __builtin_amdgcn_s_barrier();

        // ---- phase 3: read A-qm1 (8); stage B1(kt+2); MFMA q(1,0)
        #pragma unroll
        for (int i = 0; i < 4; i++)
            #pragma unroll
            for (int ks = 0; ks < 2; ks++)
                a1[i][ks] = rdA(p, wm * 128 + 64 + i * 16 + l15, ks);
        if (kt + 2 < NKT) stage(1, p, 1, kt + 2);
        __builtin_amdgcn_sched_barrier(0);
        __builtin_amdgcn_s_barrier();
        __builtin_amdgcn_s_setprio(1);
        #pragma unroll
        for (int i = 0; i < 4; i++)
            #pragma unroll
            for (int nf = 0; nf < 2; nf++) {
                acc[4 + i][nf] = __builtin_amdgcn_mfma_f32_16x16x32_f16(a1[i][0], bf[nf][0], acc[4 + i][nf], 0, 0, 0);
                acc[4 + i][nf] = __builtin_amdgcn_mfma_f32_16x16x32_f16(a1[i][1], bf[nf][1], acc[4 + i][nf], 0, 0, 0);
            }
        __builtin_amdgcn_s_setprio(0);
        __builtin_amdgcn_sched_barrier(0);
        __builtin_amdgcn_s_barrier();

        // ---- phase 4: stage A0(kt+2); counted vmcnt; MFMA q(1,1)
        if (kt + 2 < NKT) stage(0, p, 0, kt + 2);
        if (kt >= NKT - 3) asm volatile("s_waitcnt vmcnt(0)" ::: "memory");
        else               asm volatile("s_waitcnt vmcnt(6)" ::: "memory");
        __builtin_amdgcn_sched_barrier(0);
        __builtin_amdgcn_s_barrier();
        __builtin_amdgcn_s_setprio(1);
        #pragma unroll
        for (int i = 0; i < 4; i++)
            #pragma unroll
            for (int nf = 2; nf < 4; nf++) {
                acc[4 + i][nf] = __builtin_amdgcn_mfma_f32_16x16x32_f16(a1[i][0], bf[nf][0], acc[4 + i][nf], 0, 0, 0);
                acc[4 + i][nf] = __builtin_amdgcn_mfma_f32_16x16x32_f16(a1[i][1], bf[nf][1], acc[4 + i][nf], 0, 0, 0);
            }
        __builtin_amdgcn_s_setprio(0);
        __builtin_amdgcn_sched_barrier(0);
        __builtin_amdgcn_s_barrier();
    }

    // epilogue: C/D layout (HW-verified): col = lane&15, row = 4*(lane>>4)+reg
    #pragma unroll
    for (int i = 0; i < 8; i++) {
        int r0 = rb + wm * 128 + i * 16 + l4 * 4;
        #pragma unroll
        for (int nf = 0; nf < 4; nf++) {
            int c = cb + wn * 64 + nf * 16 + l15;
            #pragma unroll
            for (int reg = 0; reg < 4; reg++)
                C[(size_t)(r0 + reg) * JJ + c] = acc[i][nf][reg];
        }
    }
}

// ---------------- 128x128 f16 GEMM (kept for the small projection) ----------------
template<int TERMS>
__global__ __launch_bounds__(256, 2)
void gemm_f16(const __half* __restrict__ Ahi, const __half* __restrict__ Alo,
              const __half* __restrict__ Bhi, const __half* __restrict__ Blo,
              float* __restrict__ C, int K, int ldc, int ncb_log2)
{
    __shared__ __align__(16) __half lds[2][4][8][512];
    const int tid  = threadIdx.x;
    const int lane = tid & 63;
    const int wave = tid >> 6;
    const int l15  = lane & 15, l4 = lane >> 4;

    const int nwg  = gridDim.x;
    const int orig = blockIdx.x;
    const int wg   = (orig & 7) * (nwg >> 3) + (orig >> 3);
    const int rb = (wg >> ncb_log2) * 128;
    const int cb = (wg & ((1 << ncb_log2) - 1)) * 128;

    auto stage = [&](int buf, int ks) {
        const int k0 = ks * 32;
        #pragma unroll
        for (int qq = 0; qq < 2; qq++) {
            int g = wave * 2 + qq;
            size_t aoff = (size_t)(rb + g * 16 + l15) * K + (k0 + 8 * l4);
            gload16(Ahi + aoff, &lds[buf][0][g][0]);
            if constexpr (TERMS == 3) gload16(Alo + aoff, &lds[buf][1][g][0]);
            size_t boff = (size_t)(cb + g * 16 + l15) * K + (k0 + 8 * l4);
            gload16(Bhi + boff, &lds[buf][2][g][0]);
            if constexpr (TERMS == 3) gload16(Blo + boff, &lds[buf][3][g][0]);
        }
    };

    const int wave_r = (wave >> 1) * 64;
    const int wave_c = (wave & 1) * 64;
    const int ag0 = wave_r >> 4;
    const int bg0 = wave_c >> 4;

    f32x4 acc[4][4] = {};
    const int nks = K >> 5;
    stage(0, 0);
    int buf = 0;
    for (int ks = 0; ks < nks; ks++) {
        __syncthreads();
        if (ks + 1 < nks) stage(buf ^ 1, ks + 1);
        f16x8 ah[4], bh[4], al[4], bl[4];
        #pragma unroll
        for (int i = 0; i < 4; i++) {
            ah[i] = *(const f16x8*)&lds[buf][0][ag0 + i][lane * 8];
            bh[i] = *(const f16x8*)&lds[buf][2][bg0 + i][lane * 8];
            if constexpr (TERMS == 3) {
                al[i] = *(const f16x8*)&lds[buf][1][ag0 + i][lane * 8];
                bl[i] = *(const f16x8*)&lds[buf][3][bg0 + i][lane * 8];
            }
        }
        #pragma unroll
        for (int m = 0; m < 4; m++)
            #pragma unroll
            for (int n = 0; n < 4; n++) {
                acc[m][n] = __builtin_amdgcn_mfma_f32_16x16x32_f16(ah[m], bh[n], acc[m][n], 0, 0, 0);
                if constexpr (TERMS == 3) {
                    acc[m][n] = __builtin_amdgcn_mfma_f32_16x16x32_f16(ah[m], bl[n], acc[m][n], 0, 0, 0);
                    acc[m][n] = __builtin_amdgcn_mfma_f32_16x16x32_f16(al[m], bh[n], acc[m][n], 0, 0, 0);
                }
            }
        buf ^= 1;
    }
    #pragma unroll
    for (int m = 0; m < 4; m++)
        #pragma unroll
        for (int n = 0; n < 4; n++) {
            int r0 = rb + wave_r + m * 16 + l4 * 4;
            int c  = cb + wave_c + n * 16 + l15;
            #pragma unroll
            for (int reg = 0; reg < 4; reg++)
                C[(size_t)(r0 + reg) * ldc + c] = acc[m][n][reg];
        }
}

// ---------------- LIF over T for mem + gate paths ----------------
__global__ __launch_bounds__(256)
void lif_kernel(const float* __restrict__ mi_gi, __half* __restrict__ mv,
                float* __restrict__ gmask, const float* __restrict__ gate_thr)
{
    int idx = blockIdx.x * 256 + threadIdx.x;   // n*1024 + m
    int n = idx >> 10, m = idx & 1023;
    const float* pm = mi_gi + (size_t)n * JJ + m;
    const size_t tstride = (size_t)NN * JJ;
    __half* pv = mv + idx;
    float vm = 0.f, vg = 0.f, cnt = 0.f;
    #pragma unroll
    for (int t = 0; t < TT; t++) {
        float im = pm[(size_t)t * tstride];
        vm = 0.99f * vm + im;
        pv[(size_t)t * (NN * MM)] = __float2half(vm);   // pre-reset trace
        if (vm >= 1.0f) vm -= 1.0f;
        float ig = pm[(size_t)t * tstride + MM];
        vg = 0.9f * vg + ig;
        if (vg >= 1.0f) { vg -= 1.0f; cnt += 1.0f; }
    }
    float gs = cnt * 0.0625f;
    gmask[idx] = 1.0f / (1.0f + expf(-10.0f * (gs - gate_thr[0])));
}

// ---------------- attention scores + softmax + mem_read (one block per n) ----------------
__global__ __launch_bounds__(256)
void attn_memread(const __half* __restrict__ mv, const float* __restrict__ wq,
                  const float* __restrict__ gmask, __half* __restrict__ mem_read)
{
    int n = blockIdx.x;
    __shared__ __align__(16) __half smv[TT][1032];
    __shared__ float sw[HH][TT];
    __shared__ float ssm[HH][TT];
    int tid = threadIdx.x;

    for (int t = 0; t < TT; t++) {
        const ushort4* src = (const ushort4*)(mv + ((size_t)t * NN + n) * MM);
        ((ushort4*)&smv[t][0])[tid] = src[tid];
    }
    __syncthreads();

    if (tid < 128) {
        int h = tid >> 4, t = tid & 15;
        const float* w = wq + h * MM;
        float acc = 0.f;
        for (int m = 0; m < MM; m += 2) {
            float2 v = __half22float2(*(const __half2*)&smv[t][m]);
            acc = fmaf(v.x, w[m], acc);
            acc = fmaf(v.y, w[m + 1], acc);
        }
        sw[h][t] = acc;
    }
    __syncthreads();
    if (tid < 8) {
        int h = tid;
        float mx = -1e30f;
        for (int t = 0; t < TT; t++) mx = fmaxf(mx, sw[h][t]);
        float s = 0.f;
        for (int t = 0; t < TT; t++) { float e = __expf(sw[h][t] - mx); ssm[h][t] = e; s += e; }
        float inv = 1.0f / s;
        for (int t = 0; t < TT; t++) ssm[h][t] *= inv;
    }
    __syncthreads();

    const float* gm = gmask + (size_t)n * MM;
    #pragma unroll
    for (int mm = 0; mm < 4; mm++) {
        int m = tid + mm * 256;
        int h = m >> 7;
        float acc = 0.f;
        #pragma unroll
        for (int t = 0; t < TT; t++) acc = fmaf(__half2float(smv[t][m]), ssm[h][t], acc);
        acc *= gm[m];
        mem_read[(size_t)n * MM + m] = __float2half(acc);
    }
}

// ---------------- LayerNorm + residual broadcast over T (one block per n) ----------------
__global__ __launch_bounds__(256)
void ln_add(const float* __restrict__ mem_out, const float* __restrict__ x,
            const float* __restrict__ gamma, const float* __restrict__ beta,
            const float* __restrict__ mmix, float* __restrict__ out)
{
    int n = blockIdx.x, tid = threadIdx.x;
    int lane = tid & 63, wave = tid >> 6;
    __shared__ float sred[10];
    float4 v = ((const float4*)(mem_out + (size_t)n * DD))[tid];
    float s  = v.x + v.y + v.z + v.w;
    float ss = v.x * v.x + v.y * v.y + v.z * v.z + v.w * v.w;
    #pragma unroll
    for (int o = 32; o > 0; o >>= 1) { s += __shfl_down(s, o, 64); ss += __shfl_down(ss, o, 64); }
    if (lane == 0) { sred[wave * 2] = s; sred[wave * 2 + 1] = ss; }
    __syncthreads();
    if (tid == 0) {
        float S = 0.f, SS = 0.f;
        for (int w = 0; w < 4; w++) { S += sred[w * 2]; SS += sred[w * 2 + 1]; }
        float mu = S * (1.0f / DD);
        float var = SS * (1.0f / DD) - mu * mu;
        sred[8] = mu;
        sred[9] = rsqrtf(var + 1e-5f);
    }
    __syncthreads();
    float mu = sred[8], rs = sred[9];
    float4 g = ((const float4*)gamma)[tid];
    float4 b = ((const float4*)beta)[tid];
    float4 nv;
    nv.x = (v.x - mu) * rs * g.x + b.x;
    nv.y = (v.y - mu) * rs * g.y + b.y;
    nv.z = (v.z - mu) * rs * g.z + b.z;
    nv.w = (v.w - mu) * rs * g.w + b.w;
    float mix = 1.0f / (1.0f + expf(-mmix[0]));
    for (int t = 0; t < TT; t++) {
        size_t off = ((size_t)t * NN + n) * DD;
        float4 xv = ((const float4*)(x + off))[tid];
        float4 o;
        o.x = xv.x + mix * nv.x;
        o.y = xv.y + mix * nv.y;
        o.z = xv.z + mix * nv.z;
        o.w = xv.w + mix * nv.w;
        ((float4*)(out + off))[tid] = o;
    }
}

__global__ void ws_sentinel(float* out) { out[0] = 12345.0f; }

extern "C" void kernel_launch(void* const* d_in, const int* in_sizes, int n_in,
                              void* d_out, int out_size, void* d_ws, size_t ws_size,
                              hipStream_t stream)
{
    const float* x     = (const float*)d_in[0];
    const float* Wto   = (const float*)d_in[1];
    const float* Wg    = (const float*)d_in[2];
    const float* Wrk   = (const float*)d_in[3];
    const float* Wfrom = (const float*)d_in[4];
    const float* q     = (const float*)d_in[5];
    const float* gthr  = (const float*)d_in[6];
    const float* gamma = (const float*)d_in[7];
    const float* beta  = (const float*)d_in[8];
    const float* mmix  = (const float*)d_in[9];
    float* out = (float*)d_out;

    char* w = (char*)d_ws;
    size_t off = 0;
    auto alloc = [&](size_t bytes) -> void* {
        void* p = w + off;
        off += (bytes + 255) & ~(size_t)255;
        return p;
    };
    __half* x_hi   = (__half*)alloc((size_t)ROWS * DD * 2);
    __half* x_lo   = (__half*)alloc((size_t)ROWS * DD * 2);
    __half* wc_hi  = (__half*)alloc((size_t)JJ * DD * 2);
    __half* wc_lo  = (__half*)alloc((size_t)JJ * DD * 2);
    __half* wf_hi  = (__half*)alloc((size_t)DD * MM * 2);
    __half* wf_lo  = (__half*)alloc((size_t)DD * MM * 2);
    float*  wq     = (float*) alloc((size_t)HH * MM * 4);
    float*  mi_gi  = (float*) alloc((size_t)ROWS * JJ * 4);
    __half* mv     = (__half*)alloc((size_t)TT * NN * MM * 2);
    float*  gmask  = (float*) alloc((size_t)NN * MM * 4);
    __half* m_read = (__half*)alloc((size_t)NN * MM * 2);
    float*  m_out  = (float*) alloc((size_t)NN * DD * 4);

    if (off > ws_size) {
        ws_sentinel<<<1, 1, 0, stream>>>(out);
        return;
    }

    // allow 128 KiB dynamic LDS for gemm8p (deterministic, capture-safe)
    hipFuncSetAttribute((const void*)gemm8p, hipFuncAttributeMaxDynamicSharedMemorySize, 131072);

    // 1) packs
    pack_hilo<<<(ROWS * DD / 4 + 255) / 256, 256, 0, stream>>>(x, x_hi, x_lo, ROWS * DD / 4);
    pack_hilo<<<(MM * DD / 4 + 255) / 256, 256, 0, stream>>>(Wto, wc_hi, wc_lo, MM * DD / 4);
    pack_hilo<<<(MM * DD / 4 + 255) / 256, 256, 0, stream>>>(Wg, wc_hi + (size_t)MM * DD, wc_lo + (size_t)MM * DD, MM * DD / 4);
    pack_hilo<<<(DD * MM / 4 + 255) / 256, 256, 0, stream>>>(Wfrom, wf_hi, wf_lo, DD * MM / 4);
    compute_wq<<<dim3(4, 8), 256, 0, stream>>>(Wrk, q, wq);

    // 2) big 3-term f16 GEMM via 8-phase 256^2 template (virtual K'=3072)
    gemm8p<<<(ROWS / 256) * (JJ / 256), 512, 131072, stream>>>(x_hi, x_lo, wc_hi, wc_lo, mi_gi);

    // 3) LIF scan (mem + gate)
    lif_kernel<<<NN * MM / 256, 256, 0, stream>>>(mi_gi, mv, gmask, gthr);

    // 4) attention scores + softmax + gated mem_read
    attn_memread<<<NN, 256, 0, stream>>>(mv, wq, gmask, m_read);

    // 5) mem_out = mem_read @ W_from^T  (2048 x 1024, K=1024), single-term f16
    gemm_f16<1><<<(NN / 128) * (DD / 128), 256, 0, stream>>>(m_read, m_read, wf_hi, wf_hi, m_out, MM, DD, 3);

    // 6) LayerNorm + residual broadcast over T
    ln_add<<<NN, 256, 0, stream>>>(m_out, x, gamma, beta, mmix, out);
}

// Round 5
// 608.074 us; speedup vs baseline: 1.3054x; 1.0702x over previous
//
#include <hip/hip_runtime.h>
#include <hip/hip_bf16.h>
#include <hip/hip_fp16.h>

// Problem constants
#define TT 16
#define NN 2048          // B*S
#define DD 1024
#define MM 1024
#define HH 8
#define ROWS 32768       // T*N
#define JJ 2048          // 2*M (mi | gi packed)

typedef _Float16 f16x8 __attribute__((ext_vector_type(8)));
typedef float f32x4 __attribute__((ext_vector_type(4)));

#define SB  __builtin_amdgcn_sched_barrier(0)
#define BAR __builtin_amdgcn_s_barrier()

__device__ __forceinline__ void gload16(const void* g, void* l) {
    __builtin_amdgcn_global_load_lds((const __attribute__((address_space(1))) void*)g,
                                     (__attribute__((address_space(3))) void*)l, 16, 0, 0);
}

// ---------------- pack fp32 -> f16 hi only ----------------
__global__ __launch_bounds__(256) void pack_hi(const float* __restrict__ in,
                                               __half* __restrict__ hi, long n4) {
    long i = (long)blockIdx.x * 256 + threadIdx.x;
    if (i >= n4) return;
    float4 v = ((const float4*)in)[i];
    ushort4 H = { __half_as_ushort(__float2half(v.x)), __half_as_ushort(__float2half(v.y)),
                  __half_as_ushort(__float2half(v.z)), __half_as_ushort(__float2half(v.w)) };
    ((ushort4*)hi)[i] = H;
}

// ---------------- pack fp32 -> f16 hi/lo ----------------
__global__ __launch_bounds__(256) void pack_hilo(const float* __restrict__ in,
                                                 __half* __restrict__ hi,
                                                 __half* __restrict__ lo, long n4) {
    long i = (long)blockIdx.x * 256 + threadIdx.x;
    if (i >= n4) return;
    float4 v = ((const float4*)in)[i];
    __half h0 = __float2half(v.x), h1 = __float2half(v.y);
    __half h2 = __float2half(v.z), h3 = __float2half(v.w);
    __half l0 = __float2half(v.x - __half2float(h0));
    __half l1 = __float2half(v.y - __half2float(h1));
    __half l2 = __float2half(v.z - __half2float(h2));
    __half l3 = __float2half(v.w - __half2float(h3));
    ushort4 H = { __half_as_ushort(h0), __half_as_ushort(h1), __half_as_ushort(h2), __half_as_ushort(h3) };
    ushort4 L = { __half_as_ushort(l0), __half_as_ushort(l1), __half_as_ushort(l2), __half_as_ushort(l3) };
    ((ushort4*)hi)[i] = H;
    ((ushort4*)lo)[i] = L;
}

// ---------------- wq[h][m] = scale * sum_hd q[h,hd]*Wrk[h*128+hd, m] ----------------
__global__ __launch_bounds__(256) void compute_wq(const float* __restrict__ Wrk,
                                                  const float* __restrict__ q,
                                                  float* __restrict__ wq) {
    int m = blockIdx.x * 256 + threadIdx.x;   // 0..1023
    int h = blockIdx.y;                        // 0..7
    const float* qh = q + h * 128;
    const float* wr = Wrk + (size_t)h * 128 * MM + m;
    float acc = 0.f;
    for (int hd = 0; hd < 128; hd++) acc = fmaf(qh[hd], wr[(size_t)hd * MM], acc);
    wq[h * MM + m] = acc * 0.08838834764831845f;   // 1/sqrt(128)
}

// =============================================================================
// 256x256 3-term f16 GEMM, triplet-reordered: per k0 (BK=32):
//   {Ahi*Bh, Ahi*Bl, Alo*Bh} with A frags held over phases 1-4 and Bh over 1-6.
// 512 threads (8 waves, 2Mx4N), 128 KiB LDS (4 tiles x 2 parity x 16KB),
// 6 phases/triplet, counted vmcnt(2)/vmcnt(4), no LDS swizzle
// ([256][64B] rows hit all 32 banks uniformly = conflict-free b128).
// =============================================================================
__global__ __launch_bounds__(512, 2)
void gemm8p(const __half* __restrict__ Ahi, const __half* __restrict__ Alo,
            const __half* __restrict__ Bhi, const __half* __restrict__ Blo,
            float* __restrict__ C)
{
    extern __shared__ __align__(16) char smem[];
    char* AHb = smem;                 // [2 parity][16384 B] each
    char* ALb = smem + 32768;
    char* BHb = smem + 65536;
    char* BLb = smem + 98304;

    const int tid = threadIdx.x, lane = tid & 63, wave = tid >> 6;
    const int l15 = lane & 15, l4 = lane >> 4;
    const int wm = wave >> 2, wn = wave & 3;

    // XCD-contiguous swizzle (1024 blocks), col-fastest within chunk.
    const int orig = blockIdx.x;
    const int wg   = (orig & 7) * 128 + (orig >> 3);
    const int rb   = (wg >> 3) * 256;
    const int cb   = (wg & 7) * 256;

    // Stage 8KB slice j of a 16KB tile (256 rows x 64B = BK 32 f16).
    // Linear LDS dest (wave-uniform base + lane*16); per-lane global source.
    auto stageU = [&](const __half* src, int row0, char* dstbase, int par, int kt, int j) {
        int t   = j * 512 + tid;            // 16B chunk 0..1023
        int row = t >> 2;
        int kb  = (t & 3) * 16;
        const char* g = (const char*)(src + (size_t)(row0 + row) * 1024 + kt * 32) + kb;
        gload16(g, dstbase + par * 16384 + (size_t)(j * 512 + wave * 64) * 16);
    };
    auto rdT = [&](const char* base, int par, int row) -> f16x8 {
        return *(const f16x8*)(base + par * 16384 + row * 64 + l4 * 16);
    };

    f32x4 acc[8][4] = {};
    const int NKT = 32;                     // k0 triplets

    // Prologue: stage triplet 0 (parity 0): queue [AH2, AL2, BH2, BL2]
    stageU(Ahi, rb, AHb, 0, 0, 0); stageU(Ahi, rb, AHb, 0, 0, 1);
    stageU(Alo, rb, ALb, 0, 0, 0); stageU(Alo, rb, ALb, 0, 0, 1);
    stageU(Bhi, cb, BHb, 0, 0, 0); stageU(Bhi, cb, BHb, 0, 0, 1);
    stageU(Blo, cb, BLb, 0, 0, 0); stageU(Blo, cb, BLb, 0, 0, 1);
    asm volatile("s_waitcnt vmcnt(2)" ::: "memory");   // AH,AL,BH done
    SB; BAR;

    for (int kt = 0; kt < NKT; kt++) {
        const int p = kt & 1, pn = p ^ 1;
        const bool pre = (kt + 1 < NKT);
        f16x8 a[8], bh[4], bl[4];

        // ---- ph1: read AH(8)+BH(4); stage AH(kt+1); MFMA a[0..3] x bh
        #pragma unroll
        for (int i = 0; i < 8; i++) a[i] = rdT(AHb, p, wm * 128 + i * 16 + l15);
        #pragma unroll
        for (int n = 0; n < 4; n++) bh[n] = rdT(BHb, p, wn * 64 + n * 16 + l15);
        if (pre) { stageU(Ahi, rb, AHb, pn, kt + 1, 0); stageU(Ahi, rb, AHb, pn, kt + 1, 1); }
        SB; BAR;
        __builtin_amdgcn_s_setprio(1);
        #pragma unroll
        for (int i = 0; i < 4; i++)
            #pragma unroll
            for (int n = 0; n < 4; n++)
                acc[i][n] = __builtin_amdgcn_mfma_f32_16x16x32_f16(a[i], bh[n], acc[i][n], 0, 0, 0);
        __builtin_amdgcn_s_setprio(0);
        SB; BAR;

        // ---- ph2: stage AL(kt+1); MFMA a[4..7] x bh; tail: ensure BL(kt) done
        if (pre) { stageU(Alo, rb, ALb, pn, kt + 1, 0); stageU(Alo, rb, ALb, pn, kt + 1, 1); }
        SB; BAR;
        __builtin_amdgcn_s_setprio(1);
        #pragma unroll
        for (int i = 0; i < 4; i++)
            #pragma unroll
            for (int n = 0; n < 4; n++)
                acc[4 + i][n] = __builtin_amdgcn_mfma_f32_16x16x32_f16(a[4 + i], bh[n], acc[4 + i][n], 0, 0, 0);
        __builtin_amdgcn_s_setprio(0);
        SB;
        if (pre) asm volatile("s_waitcnt vmcnt(4)" ::: "memory");  // queue: [BLk2,AH+1 2,AL+1 2] -> BLk done
        else     asm volatile("s_waitcnt vmcnt(0)" ::: "memory");
        SB; BAR;

        // ---- ph3: read BL(4); stage BH(kt+1); MFMA a[0..3] x bl
        #pragma unroll
        for (int n = 0; n < 4; n++) bl[n] = rdT(BLb, p, wn * 64 + n * 16 + l15);
        if (pre) { stageU(Bhi, cb, BHb, pn, kt + 1, 0); stageU(Bhi, cb, BHb, pn, kt + 1, 1); }
        SB; BAR;
        __builtin_amdgcn_s_setprio(1);
        #pragma unroll
        for (int i = 0; i < 4; i++)
            #pragma unroll
            for (int n = 0; n < 4; n++)
                acc[i][n] = __builtin_amdgcn_mfma_f32_16x16x32_f16(a[i], bl[n], acc[i][n], 0, 0, 0);
        __builtin_amdgcn_s_setprio(0);
        SB; BAR;

        // ---- ph4: stage BL(kt+1); MFMA a[4..7] x bl
        if (pre) { stageU(Blo, cb, BLb, pn, kt + 1, 0); stageU(Blo, cb, BLb, pn, kt + 1, 1); }
        SB; BAR;
        __builtin_amdgcn_s_setprio(1);
        #pragma unroll
        for (int i = 0; i < 4; i++)
            #pragma unroll
            for (int n = 0; n < 4; n++)
                acc[4 + i][n] = __builtin_amdgcn_mfma_f32_16x16x32_f16(a[4 + i], bl[n], acc[4 + i][n], 0, 0, 0);
        __builtin_amdgcn_s_setprio(0);
        SB; BAR;

        // ---- ph5: read AL(8) (reuse a[]); MFMA a[0..3] x bh
        #pragma unroll
        for (int i = 0; i < 8; i++) a[i] = rdT(ALb, p, wm * 128 + i * 16 + l15);
        SB; BAR;
        __builtin_amdgcn_s_setprio(1);
        #pragma unroll
        for (int i = 0; i < 4; i++)
            #pragma unroll
            for (int n = 0; n < 4; n++)
                acc[i][n] = __builtin_amdgcn_mfma_f32_16x16x32_f16(a[i], bh[n], acc[i][n], 0, 0, 0);
        __builtin_amdgcn_s_setprio(0);
        SB; BAR;

        // ---- ph6: MFMA a[4..7] x bh; tail: next triplet's AH,AL,BH done
        __builtin_amdgcn_s_setprio(1);
        #pragma unroll
        for (int i = 0; i < 4; i++)
            #pragma unroll
            for (int n = 0; n < 4; n++)
                acc[4 + i][n] = __builtin_amdgcn_mfma_f32_16x16x32_f16(a[4 + i], bh[n], acc[4 + i][n], 0, 0, 0);
        __builtin_amdgcn_s_setprio(0);
        SB;
        asm volatile("s_waitcnt vmcnt(2)" ::: "memory");   // no-op on last triplet
        SB; BAR;
    }

    // epilogue: C/D layout (HW-verified): col = lane&15, row = 4*(lane>>4)+reg
    #pragma unroll
    for (int i = 0; i < 8; i++) {
        int r0 = rb + wm * 128 + i * 16 + l4 * 4;
        #pragma unroll
        for (int nf = 0; nf < 4; nf++) {
            int c = cb + wn * 64 + nf * 16 + l15;
            #pragma unroll
            for (int reg = 0; reg < 4; reg++)
                C[(size_t)(r0 + reg) * JJ + c] = acc[i][nf][reg];
        }
    }
}

// ---------------- 128x128 f16 GEMM (kept for the small projection) ----------------
template<int TERMS>
__global__ __launch_bounds__(256, 2)
void gemm_f16(const __half* __restrict__ Ahi, const __half* __restrict__ Alo,
              const __half* __restrict__ Bhi, const __half* __restrict__ Blo,
              float* __restrict__ C, int K, int ldc, int ncb_log2)
{
    __shared__ __align__(16) __half lds[2][4][8][512];
    const int tid  = threadIdx.x;
    const int lane = tid & 63;
    const int wave = tid >> 6;
    const int l15  = lane & 15, l4 = lane >> 4;

    const int nwg  = gridDim.x;
    const int orig = blockIdx.x;
    const int wg   = (orig & 7) * (nwg >> 3) + (orig >> 3);
    const int rb = (wg >> ncb_log2) * 128;
    const int cb = (wg & ((1 << ncb_log2) - 1)) * 128;

    auto stage = [&](int buf, int ks) {
        const int k0 = ks * 32;
        #pragma unroll
        for (int qq = 0; qq < 2; qq++) {
            int g = wave * 2 + qq;
            size_t aoff = (size_t)(rb + g * 16 + l15) * K + (k0 + 8 * l4);
            gload16(Ahi + aoff, &lds[buf][0][g][0]);
            if constexpr (TERMS == 3) gload16(Alo + aoff, &lds[buf][1][g][0]);
            size_t boff = (size_t)(cb + g * 16 + l15) * K + (k0 + 8 * l4);
            gload16(Bhi + boff, &lds[buf][2][g][0]);
            if constexpr (TERMS == 3) gload16(Blo + boff, &lds[buf][3][g][0]);
        }
    };

    const int wave_r = (wave >> 1) * 64;
    const int wave_c = (wave & 1) * 64;
    const int ag0 = wave_r >> 4;
    const int bg0 = wave_c >> 4;

    f32x4 acc[4][4] = {};
    const int nks = K >> 5;
    stage(0, 0);
    int buf = 0;
    for (int ks = 0; ks < nks; ks++) {
        __syncthreads();
        if (ks + 1 < nks) stage(buf ^ 1, ks + 1);
        f16x8 ah[4], bh[4], al[4], bl[4];
        #pragma unroll
        for (int i = 0; i < 4; i++) {
            ah[i] = *(const f16x8*)&lds[buf][0][ag0 + i][lane * 8];
            bh[i] = *(const f16x8*)&lds[buf][2][bg0 + i][lane * 8];
            if constexpr (TERMS == 3) {
                al[i] = *(const f16x8*)&lds[buf][1][ag0 + i][lane * 8];
                bl[i] = *(const f16x8*)&lds[buf][3][bg0 + i][lane * 8];
            }
        }
        #pragma unroll
        for (int m = 0; m < 4; m++)
            #pragma unroll
            for (int n = 0; n < 4; n++) {
                acc[m][n] = __builtin_amdgcn_mfma_f32_16x16x32_f16(ah[m], bh[n], acc[m][n], 0, 0, 0);
                if constexpr (TERMS == 3) {
                    acc[m][n] = __builtin_amdgcn_mfma_f32_16x16x32_f16(ah[m], bl[n], acc[m][n], 0, 0, 0);
                    acc[m][n] = __builtin_amdgcn_mfma_f32_16x16x32_f16(al[m], bh[n], acc[m][n], 0, 0, 0);
                }
            }
        buf ^= 1;
    }
    #pragma unroll
    for (int m = 0; m < 4; m++)
        #pragma unroll
        for (int n = 0; n < 4; n++) {
            int r0 = rb + wave_r + m * 16 + l4 * 4;
            int c  = cb + wave_c + n * 16 + l15;
            #pragma unroll
            for (int reg = 0; reg < 4; reg++)
                C[(size_t)(r0 + reg) * ldc + c] = acc[m][n][reg];
        }
}

// ---------------- LIF over T for mem + gate paths ----------------
__global__ __launch_bounds__(256)
void lif_kernel(const float* __restrict__ mi_gi, __half* __restrict__ mv,
                float* __restrict__ gmask, const float* __restrict__ gate_thr)
{
    int idx = blockIdx.x * 256 + threadIdx.x;   // n*1024 + m
    int n = idx >> 10, m = idx & 1023;
    const float* pm = mi_gi + (size_t)n * JJ + m;
    const size_t tstride = (size_t)NN * JJ;
    __half* pv = mv + idx;
    float vm = 0.f, vg = 0.f, cnt = 0.f;
    #pragma unroll
    for (int t = 0; t < TT; t++) {
        float im = pm[(size_t)t * tstride];
        vm = 0.99f * vm + im;
        pv[(size_t)t * (NN * MM)] = __float2half(vm);   // pre-reset trace
        if (vm >= 1.0f) vm -= 1.0f;
        float ig = pm[(size_t)t * tstride + MM];
        vg = 0.9f * vg + ig;
        if (vg >= 1.0f) { vg -= 1.0f; cnt += 1.0f; }
    }
    float gs = cnt * 0.0625f;
    gmask[idx] = 1.0f / (1.0f + expf(-10.0f * (gs - gate_thr[0])));
}

// ---------------- attention scores + softmax + mem_read (one block per n) ----------------
__global__ __launch_bounds__(256)
void attn_memread(const __half* __restrict__ mv, const float* __restrict__ wq,
                  const float* __restrict__ gmask, __half* __restrict__ mem_read)
{
    int n = blockIdx.x;
    __shared__ __align__(16) __half smv[TT][1032];
    __shared__ float sw[HH][TT];
    __shared__ float ssm[HH][TT];
    int tid = threadIdx.x;

    for (int t = 0; t < TT; t++) {
        const ushort4* src = (const ushort4*)(mv + ((size_t)t * NN + n) * MM);
        ((ushort4*)&smv[t][0])[tid] = src[tid];
    }
    __syncthreads();

    if (tid < 128) {
        int h = tid >> 4, t = tid & 15;
        const float* w = wq + h * MM;
        float acc = 0.f;
        for (int m = 0; m < MM; m += 2) {
            float2 v = __half22float2(*(const __half2*)&smv[t][m]);
            acc = fmaf(v.x, w[m], acc);
            acc = fmaf(v.y, w[m + 1], acc);
        }
        sw[h][t] = acc;
    }
    __syncthreads();
    if (tid < 8) {
        int h = tid;
        float mx = -1e30f;
        for (int t = 0; t < TT; t++) mx = fmaxf(mx, sw[h][t]);
        float s = 0.f;
        for (int t = 0; t < TT; t++) { float e = __expf(sw[h][t] - mx); ssm[h][t] = e; s += e; }
        float inv = 1.0f / s;
        for (int t = 0; t < TT; t++) ssm[h][t] *= inv;
    }
    __syncthreads();

    const float* gm = gmask + (size_t)n * MM;
    #pragma unroll
    for (int mm = 0; mm < 4; mm++) {
        int m = tid + mm * 256;
        int h = m >> 7;
        float acc = 0.f;
        #pragma unroll
        for (int t = 0; t < TT; t++) acc = fmaf(__half2float(smv[t][m]), ssm[h][t], acc);
        acc *= gm[m];
        mem_read[(size_t)n * MM + m] = __float2half(acc);
    }
}

// ---------------- LayerNorm + residual broadcast over T (one block per n) ----------------
__global__ __launch_bounds__(256)
void ln_add(const float* __restrict__ mem_out, const float* __restrict__ x,
            const float* __restrict__ gamma, const float* __restrict__ beta,
            const float* __restrict__ mmix, float* __restrict__ out)
{
    int n = blockIdx.x, tid = threadIdx.x;
    int lane = tid & 63, wave = tid >> 6;
    __shared__ float sred[10];
    float4 v = ((const float4*)(mem_out + (size_t)n * DD))[tid];
    float s  = v.x + v.y + v.z + v.w;
    float ss = v.x * v.x + v.y * v.y + v.z * v.z + v.w * v.w;
    #pragma unroll
    for (int o = 32; o > 0; o >>= 1) { s += __shfl_down(s, o, 64); ss += __shfl_down(ss, o, 64); }
    if (lane == 0) { sred[wave * 2] = s; sred[wave * 2 + 1] = ss; }
    __syncthreads();
    if (tid == 0) {
        float S = 0.f, SS = 0.f;
        for (int w = 0; w < 4; w++) { S += sred[w * 2]; SS += sred[w * 2 + 1]; }
        float mu = S * (1.0f / DD);
        float var = SS * (1.0f / DD) - mu * mu;
        sred[8] = mu;
        sred[9] = rsqrtf(var + 1e-5f);
    }
    __syncthreads();
    float mu = sred[8], rs = sred[9];
    float4 g = ((const float4*)gamma)[tid];
    float4 b = ((const float4*)beta)[tid];
    float4 nv;
    nv.x = (v.x - mu) * rs * g.x + b.x;
    nv.y = (v.y - mu) * rs * g.y + b.y;
    nv.z = (v.z - mu) * rs * g.z + b.z;
    nv.w = (v.w - mu) * rs * g.w + b.w;
    float mix = 1.0f / (1.0f + expf(-mmix[0]));
    for (int t = 0; t < TT; t++) {
        size_t off = ((size_t)t * NN + n) * DD;
        float4 xv = ((const float4*)(x + off))[tid];
        float4 o;
        o.x = xv.x + mix * nv.x;
        o.y = xv.y + mix * nv.y;
        o.z = xv.z + mix * nv.z;
        o.w = xv.w + mix * nv.w;
        ((float4*)(out + off))[tid] = o;
    }
}

__global__ void ws_sentinel(float* out) { out[0] = 12345.0f; }

extern "C" void kernel_launch(void* const* d_in, const int* in_sizes, int n_in,
                              void* d_out, int out_size, void* d_ws, size_t ws_size,
                              hipStream_t stream)
{
    const float* x     = (const float*)d_in[0];
    const float* Wto   = (const float*)d_in[1];
    const float* Wg    = (const float*)d_in[2];
    const float* Wrk   = (const float*)d_in[3];
    const float* Wfrom = (const float*)d_in[4];
    const float* q     = (const float*)d_in[5];
    const float* gthr  = (const float*)d_in[6];
    const float* gamma = (const float*)d_in[7];
    const float* beta  = (const float*)d_in[8];
    const float* mmix  = (const float*)d_in[9];
    float* out = (float*)d_out;

    char* w = (char*)d_ws;
    size_t off = 0;
    auto alloc = [&](size_t bytes) -> void* {
        void* p = w + off;
        off += (bytes + 255) & ~(size_t)255;
        return p;
    };
    __half* x_hi   = (__half*)alloc((size_t)ROWS * DD * 2);     // 64 MB
    __half* x_lo   = (__half*)alloc((size_t)ROWS * DD * 2);     // 64 MB
    __half* wc_hi  = (__half*)alloc((size_t)JJ * DD * 2);       // 4 MB
    __half* wc_lo  = (__half*)alloc((size_t)JJ * DD * 2);       // 4 MB
    __half* wf_hi  = (__half*)alloc((size_t)DD * MM * 2);       // 2 MB
    float*  wq     = (float*) alloc((size_t)HH * MM * 4);
    float*  mi_gi  = (float*) alloc((size_t)ROWS * JJ * 4);     // 256 MB
    __half* mv     = (__half*)alloc((size_t)TT * NN * MM * 2);  // 64 MB
    float*  gmask  = (float*) alloc((size_t)NN * MM * 4);       // 8 MB
    __half* m_read = (__half*)alloc((size_t)NN * MM * 2);       // 4 MB
    float*  m_out  = (float*) alloc((size_t)NN * DD * 4);       // 8 MB

    if (off > ws_size) {
        ws_sentinel<<<1, 1, 0, stream>>>(out);
        return;
    }

    // allow 128 KiB dynamic LDS for gemm8p (deterministic, capture-safe)
    hipFuncSetAttribute((const void*)gemm8p, hipFuncAttributeMaxDynamicSharedMemorySize, 131072);

    // 1) packs
    pack_hilo<<<(ROWS * DD / 4 + 255) / 256, 256, 0, stream>>>(x, x_hi, x_lo, ROWS * DD / 4);
    pack_hilo<<<(MM * DD / 4 + 255) / 256, 256, 0, stream>>>(Wto, wc_hi, wc_lo, MM * DD / 4);
    pack_hilo<<<(MM * DD / 4 + 255) / 256, 256, 0, stream>>>(Wg, wc_hi + (size_t)MM * DD, wc_lo + (size_t)MM * DD, MM * DD / 4);
    pack_hi<<<(DD * MM / 4 + 255) / 256, 256, 0, stream>>>(Wfrom, wf_hi, DD * MM / 4);
    compute_wq<<<dim3(4, 8), 256, 0, stream>>>(Wrk, q, wq);

    // 2) big 3-term f16 GEMM (triplet-reordered): mi|gi = x @ [W_to;W_gate]^T
    gemm8p<<<(ROWS / 256) * (JJ / 256), 512, 131072, stream>>>(x_hi, x_lo, wc_hi, wc_lo, mi_gi);

    // 3) LIF scan (mem + gate)
    lif_kernel<<<NN * MM / 256, 256, 0, stream>>>(mi_gi, mv, gmask, gthr);

    // 4) attention scores + softmax + gated mem_read
    attn_memread<<<NN, 256, 0, stream>>>(mv, wq, gmask, m_read);

    // 5) mem_out = mem_read @ W_from^T  (2048 x 1024, K=1024), single-term f16
    gemm_f16<1><<<(NN / 128) * (DD / 128), 256, 0, stream>>>(m_read, m_read, wf_hi, wf_hi, m_out, MM, DD, 3);

    // 6) LayerNorm + residual broadcast over T
    ln_add<<<NN, 256, 0, stream>>>(m_out, x, gamma, beta, mmix, out);
}

// Round 6
// 593.258 us; speedup vs baseline: 1.3380x; 1.0250x over previous
//
#include <hip/hip_runtime.h>
#include <hip/hip_bf16.h>
#include <hip/hip_fp16.h>

// Problem constants
#define TT 16
#define NN 2048          // B*S
#define DD 1024
#define MM 1024
#define HH 8
#define ROWS 32768       // T*N
#define JJ 2048          // 2*M (mi | gi packed)

typedef _Float16 f16x8 __attribute__((ext_vector_type(8)));
typedef float f32x4 __attribute__((ext_vector_type(4)));

#define SB  __builtin_amdgcn_sched_barrier(0)
#define BAR __builtin_amdgcn_s_barrier()

__device__ __forceinline__ void gload16(const void* g, void* l) {
    __builtin_amdgcn_global_load_lds((const __attribute__((address_space(1))) void*)g,
                                     (__attribute__((address_space(3))) void*)l, 16, 0, 0);
}

// ---------------- pack fp32 -> f16 hi only ----------------
__global__ __launch_bounds__(256) void pack_hi(const float* __restrict__ in,
                                               __half* __restrict__ hi, long n4) {
    long i = (long)blockIdx.x * 256 + threadIdx.x;
    if (i >= n4) return;
    float4 v = ((const float4*)in)[i];
    ushort4 H = { __half_as_ushort(__float2half(v.x)), __half_as_ushort(__float2half(v.y)),
                  __half_as_ushort(__float2half(v.z)), __half_as_ushort(__float2half(v.w)) };
    ((ushort4*)hi)[i] = H;
}

// ---------------- pack fp32 -> f16 hi/lo ----------------
__global__ __launch_bounds__(256) void pack_hilo(const float* __restrict__ in,
                                                 __half* __restrict__ hi,
                                                 __half* __restrict__ lo, long n4) {
    long i = (long)blockIdx.x * 256 + threadIdx.x;
    if (i >= n4) return;
    float4 v = ((const float4*)in)[i];
    __half h0 = __float2half(v.x), h1 = __float2half(v.y);
    __half h2 = __float2half(v.z), h3 = __float2half(v.w);
    __half l0 = __float2half(v.x - __half2float(h0));
    __half l1 = __float2half(v.y - __half2float(h1));
    __half l2 = __float2half(v.z - __half2float(h2));
    __half l3 = __float2half(v.w - __half2float(h3));
    ushort4 H = { __half_as_ushort(h0), __half_as_ushort(h1), __half_as_ushort(h2), __half_as_ushort(h3) };
    ushort4 L = { __half_as_ushort(l0), __half_as_ushort(l1), __half_as_ushort(l2), __half_as_ushort(l3) };
    ((ushort4*)hi)[i] = H;
    ((ushort4*)lo)[i] = L;
}

// ---------------- wq[h][m] = scale * sum_hd q[h,hd]*Wrk[h*128+hd, m] ----------------
__global__ __launch_bounds__(256) void compute_wq(const float* __restrict__ Wrk,
                                                  const float* __restrict__ q,
                                                  float* __restrict__ wq) {
    int m = blockIdx.x * 256 + threadIdx.x;   // 0..1023
    int h = blockIdx.y;                        // 0..7
    const float* qh = q + h * 128;
    const float* wr = Wrk + (size_t)h * 128 * MM + m;
    float acc = 0.f;
    for (int hd = 0; hd < 128; hd++) acc = fmaf(qh[hd], wr[(size_t)hd * MM], acc);
    wq[h * MM + m] = acc * 0.08838834764831845f;   // 1/sqrt(128)
}

// =============================================================================
// 256x256 3-term f16 GEMM, triplet-reordered: per k0 (BK=32):
//   {Ahi*Bh, Ahi*Bl, Alo*Bh} with A frags held over phases 1-4 and Bh over 1-6.
// 512 threads (8 waves, 2Mx4N), 128 KiB LDS (4 tiles x 2 parity x 16KB),
// 6 phases/triplet, counted vmcnt(2)/vmcnt(4).
// T2 XOR-swizzle (slot p = j ^ ((row>>1)&3)): 16-lane groups read 16
// consecutive rows at one 16B slot; swizzle spreads them 2 dwords/bank
// (wave64 minimum). Linear gload_lds dest + inverse-swizzled global source
// + swizzled read (rule #21) -> bit-identical data, zero conflicts.
// =============================================================================
__global__ __launch_bounds__(512, 2)
void gemm8p(const __half* __restrict__ Ahi, const __half* __restrict__ Alo,
            const __half* __restrict__ Bhi, const __half* __restrict__ Blo,
            float* __restrict__ C)
{
    extern __shared__ __align__(16) char smem[];
    char* AHb = smem;                 // [2 parity][16384 B] each
    char* ALb = smem + 32768;
    char* BHb = smem + 65536;
    char* BLb = smem + 98304;

    const int tid = threadIdx.x, lane = tid & 63, wave = tid >> 6;
    const int l15 = lane & 15, l4 = lane >> 4;
    const int wm = wave >> 2, wn = wave & 3;

    // XCD-contiguous swizzle (1024 blocks), col-fastest within chunk.
    const int orig = blockIdx.x;
    const int wg   = (orig & 7) * 128 + (orig >> 3);
    const int rb   = (wg >> 3) * 256;
    const int cb   = (wg & 7) * 256;

    // Stage 8KB slice s of a 16KB tile (256 rows x 64B = BK 32 f16).
    // Linear LDS dest; global source slot inverse-permuted by the swizzle.
    auto stageU = [&](const __half* src, int row0, char* dstbase, int par, int kt, int s) {
        int t   = s * 512 + tid;            // 16B chunk 0..1023
        int row = t >> 2;
        int p   = t & 3;                    // physical slot in row
        int kb  = (p ^ ((row >> 1) & 3)) * 16;   // source k-slot bytes
        const char* g = (const char*)(src + (size_t)(row0 + row) * 1024 + kt * 32) + kb;
        gload16(g, dstbase + par * 16384 + (size_t)(s * 512 + wave * 64) * 16);
    };
    // Swizzled read: k-slot l4 lives at physical slot l4 ^ ((row>>1)&3).
    auto rdT = [&](const char* base, int par, int row) -> f16x8 {
        int p = l4 ^ ((row >> 1) & 3);
        return *(const f16x8*)(base + par * 16384 + row * 64 + p * 16);
    };

    f32x4 acc[8][4] = {};
    const int NKT = 32;                     // k0 triplets

    // Prologue: stage triplet 0 (parity 0): queue [AH2, AL2, BH2, BL2]
    stageU(Ahi, rb, AHb, 0, 0, 0); stageU(Ahi, rb, AHb, 0, 0, 1);
    stageU(Alo, rb, ALb, 0, 0, 0); stageU(Alo, rb, ALb, 0, 0, 1);
    stageU(Bhi, cb, BHb, 0, 0, 0); stageU(Bhi, cb, BHb, 0, 0, 1);
    stageU(Blo, cb, BLb, 0, 0, 0); stageU(Blo, cb, BLb, 0, 0, 1);
    asm volatile("s_waitcnt vmcnt(2)" ::: "memory");   // AH,AL,BH done
    SB; BAR;

    for (int kt = 0; kt < NKT; kt++) {
        const int p = kt & 1, pn = p ^ 1;
        const bool pre = (kt + 1 < NKT);
        f16x8 a[8], bh[4], bl[4];

        // ---- ph1: read AH(8)+BH(4); stage AH(kt+1); MFMA a[0..3] x bh
        #pragma unroll
        for (int i = 0; i < 8; i++) a[i] = rdT(AHb, p, wm * 128 + i * 16 + l15);
        #pragma unroll
        for (int n = 0; n < 4; n++) bh[n] = rdT(BHb, p, wn * 64 + n * 16 + l15);
        if (pre) { stageU(Ahi, rb, AHb, pn, kt + 1, 0); stageU(Ahi, rb, AHb, pn, kt + 1, 1); }
        SB; BAR;
        __builtin_amdgcn_s_setprio(1);
        #pragma unroll
        for (int i = 0; i < 4; i++)
            #pragma unroll
            for (int n = 0; n < 4; n++)
                acc[i][n] = __builtin_amdgcn_mfma_f32_16x16x32_f16(a[i], bh[n], acc[i][n], 0, 0, 0);
        __builtin_amdgcn_s_setprio(0);
        SB; BAR;

        // ---- ph2: stage AL(kt+1); MFMA a[4..7] x bh; tail: ensure BL(kt) done
        if (pre) { stageU(Alo, rb, ALb, pn, kt + 1, 0); stageU(Alo, rb, ALb, pn, kt + 1, 1); }
        SB; BAR;
        __builtin_amdgcn_s_setprio(1);
        #pragma unroll
        for (int i = 0; i < 4; i++)
            #pragma unroll
            for (int n = 0; n < 4; n++)
                acc[4 + i][n] = __builtin_amdgcn_mfma_f32_16x16x32_f16(a[4 + i], bh[n], acc[4 + i][n], 0, 0, 0);
        __builtin_amdgcn_s_setprio(0);
        SB;
        if (pre) asm volatile("s_waitcnt vmcnt(4)" ::: "memory");  // queue: [BLk2,AH+1 2,AL+1 2] -> BLk done
        else     asm volatile("s_waitcnt vmcnt(0)" ::: "memory");
        SB; BAR;

        // ---- ph3: read BL(4); stage BH(kt+1); MFMA a[0..3] x bl
        #pragma unroll
        for (int n = 0; n < 4; n++) bl[n] = rdT(BLb, p, wn * 64 + n * 16 + l15);
        if (pre) { stageU(Bhi, cb, BHb, pn, kt + 1, 0); stageU(Bhi, cb, BHb, pn, kt + 1, 1); }
        SB; BAR;
        __builtin_amdgcn_s_setprio(1);
        #pragma unroll
        for (int i = 0; i < 4; i++)
            #pragma unroll
            for (int n = 0; n < 4; n++)
                acc[i][n] = __builtin_amdgcn_mfma_f32_16x16x32_f16(a[i], bl[n], acc[i][n], 0, 0, 0);
        __builtin_amdgcn_s_setprio(0);
        SB; BAR;

        // ---- ph4: stage BL(kt+1); MFMA a[4..7] x bl
        if (pre) { stageU(Blo, cb, BLb, pn, kt + 1, 0); stageU(Blo, cb, BLb, pn, kt + 1, 1); }
        SB; BAR;
        __builtin_amdgcn_s_setprio(1);
        #pragma unroll
        for (int i = 0; i < 4; i++)
            #pragma unroll
            for (int n = 0; n < 4; n++)
                acc[4 + i][n] = __builtin_amdgcn_mfma_f32_16x16x32_f16(a[4 + i], bl[n], acc[4 + i][n], 0, 0, 0);
        __builtin_amdgcn_s_setprio(0);
        SB; BAR;

        // ---- ph5: read AL(8) (reuse a[]); MFMA a[0..3] x bh
        #pragma unroll
        for (int i = 0; i < 8; i++) a[i] = rdT(ALb, p, wm * 128 + i * 16 + l15);
        SB; BAR;
        __builtin_amdgcn_s_setprio(1);
        #pragma unroll
        for (int i = 0; i < 4; i++)
            #pragma unroll
            for (int n = 0; n < 4; n++)
                acc[i][n] = __builtin_amdgcn_mfma_f32_16x16x32_f16(a[i], bh[n], acc[i][n], 0, 0, 0);
        __builtin_amdgcn_s_setprio(0);
        SB; BAR;

        // ---- ph6: MFMA a[4..7] x bh; tail: next triplet's AH,AL,BH done
        __builtin_amdgcn_s_setprio(1);
        #pragma unroll
        for (int i = 0; i < 4; i++)
            #pragma unroll
            for (int n = 0; n < 4; n++)
                acc[4 + i][n] = __builtin_amdgcn_mfma_f32_16x16x32_f16(a[4 + i], bh[n], acc[4 + i][n], 0, 0, 0);
        __builtin_amdgcn_s_setprio(0);
        SB;
        asm volatile("s_waitcnt vmcnt(2)" ::: "memory");   // no-op on last triplet
        SB; BAR;
    }

    // epilogue: C/D layout (HW-verified): col = lane&15, row = 4*(lane>>4)+reg
    #pragma unroll
    for (int i = 0; i < 8; i++) {
        int r0 = rb + wm * 128 + i * 16 + l4 * 4;
        #pragma unroll
        for (int nf = 0; nf < 4; nf++) {
            int c = cb + wn * 64 + nf * 16 + l15;
            #pragma unroll
            for (int reg = 0; reg < 4; reg++)
                C[(size_t)(r0 + reg) * JJ + c] = acc[i][nf][reg];
        }
    }
}

// ---------------- 128x128 f16 GEMM (kept for the small projection) ----------------
template<int TERMS>
__global__ __launch_bounds__(256, 2)
void gemm_f16(const __half* __restrict__ Ahi, const __half* __restrict__ Alo,
              const __half* __restrict__ Bhi, const __half* __restrict__ Blo,
              float* __restrict__ C, int K, int ldc, int ncb_log2)
{
    __shared__ __align__(16) __half lds[2][4][8][512];
    const int tid  = threadIdx.x;
    const int lane = tid & 63;
    const int wave = tid >> 6;
    const int l15  = lane & 15, l4 = lane >> 4;

    const int nwg  = gridDim.x;
    const int orig = blockIdx.x;
    const int wg   = (orig & 7) * (nwg >> 3) + (orig >> 3);
    const int rb = (wg >> ncb_log2) * 128;
    const int cb = (wg & ((1 << ncb_log2) - 1)) * 128;

    auto stage = [&](int buf, int ks) {
        const int k0 = ks * 32;
        #pragma unroll
        for (int qq = 0; qq < 2; qq++) {
            int g = wave * 2 + qq;
            size_t aoff = (size_t)(rb + g * 16 + l15) * K + (k0 + 8 * l4);
            gload16(Ahi + aoff, &lds[buf][0][g][0]);
            if constexpr (TERMS == 3) gload16(Alo + aoff, &lds[buf][1][g][0]);
            size_t boff = (size_t)(cb + g * 16 + l15) * K + (k0 + 8 * l4);
            gload16(Bhi + boff, &lds[buf][2][g][0]);
            if constexpr (TERMS == 3) gload16(Blo + boff, &lds[buf][3][g][0]);
        }
    };

    const int wave_r = (wave >> 1) * 64;
    const int wave_c = (wave & 1) * 64;
    const int ag0 = wave_r >> 4;
    const int bg0 = wave_c >> 4;

    f32x4 acc[4][4] = {};
    const int nks = K >> 5;
    stage(0, 0);
    int buf = 0;
    for (int ks = 0; ks < nks; ks++) {
        __syncthreads();
        if (ks + 1 < nks) stage(buf ^ 1, ks + 1);
        f16x8 ah[4], bh[4], al[4], bl[4];
        #pragma unroll
        for (int i = 0; i < 4; i++) {
            ah[i] = *(const f16x8*)&lds[buf][0][ag0 + i][lane * 8];
            bh[i] = *(const f16x8*)&lds[buf][2][bg0 + i][lane * 8];
            if constexpr (TERMS == 3) {
                al[i] = *(const f16x8*)&lds[buf][1][ag0 + i][lane * 8];
                bl[i] = *(const f16x8*)&lds[buf][3][bg0 + i][lane * 8];
            }
        }
        #pragma unroll
        for (int m = 0; m < 4; m++)
            #pragma unroll
            for (int n = 0; n < 4; n++) {
                acc[m][n] = __builtin_amdgcn_mfma_f32_16x16x32_f16(ah[m], bh[n], acc[m][n], 0, 0, 0);
                if constexpr (TERMS == 3) {
                    acc[m][n] = __builtin_amdgcn_mfma_f32_16x16x32_f16(ah[m], bl[n], acc[m][n], 0, 0, 0);
                    acc[m][n] = __builtin_amdgcn_mfma_f32_16x16x32_f16(al[m], bh[n], acc[m][n], 0, 0, 0);
                }
            }
        buf ^= 1;
    }
    #pragma unroll
    for (int m = 0; m < 4; m++)
        #pragma unroll
        for (int n = 0; n < 4; n++) {
            int r0 = rb + wave_r + m * 16 + l4 * 4;
            int c  = cb + wave_c + n * 16 + l15;
            #pragma unroll
            for (int reg = 0; reg < 4; reg++)
                C[(size_t)(r0 + reg) * ldc + c] = acc[m][n][reg];
        }
}

// ---------------- LIF over T for mem + gate paths ----------------
__global__ __launch_bounds__(256)
void lif_kernel(const float* __restrict__ mi_gi, __half* __restrict__ mv,
                float* __restrict__ gmask, const float* __restrict__ gate_thr)
{
    int idx = blockIdx.x * 256 + threadIdx.x;   // n*1024 + m
    int n = idx >> 10, m = idx & 1023;
    const float* pm = mi_gi + (size_t)n * JJ + m;
    const size_t tstride = (size_t)NN * JJ;
    __half* pv = mv + idx;
    float vm = 0.f, vg = 0.f, cnt = 0.f;
    #pragma unroll
    for (int t = 0; t < TT; t++) {
        float im = pm[(size_t)t * tstride];
        vm = 0.99f * vm + im;
        pv[(size_t)t * (NN * MM)] = __float2half(vm);   // pre-reset trace
        if (vm >= 1.0f) vm -= 1.0f;
        float ig = pm[(size_t)t * tstride + MM];
        vg = 0.9f * vg + ig;
        if (vg >= 1.0f) { vg -= 1.0f; cnt += 1.0f; }
    }
    float gs = cnt * 0.0625f;
    gmask[idx] = 1.0f / (1.0f + expf(-10.0f * (gs - gate_thr[0])));
}

// ---------------- attention scores + softmax + mem_read (one block per n) ----------------
__global__ __launch_bounds__(256)
void attn_memread(const __half* __restrict__ mv, const float* __restrict__ wq,
                  const float* __restrict__ gmask, __half* __restrict__ mem_read)
{
    int n = blockIdx.x;
    __shared__ __align__(16) __half smv[TT][1032];
    __shared__ float sw[HH][TT];
    __shared__ float ssm[HH][TT];
    int tid = threadIdx.x;

    for (int t = 0; t < TT; t++) {
        const ushort4* src = (const ushort4*)(mv + ((size_t)t * NN + n) * MM);
        ((ushort4*)&smv[t][0])[tid] = src[tid];
    }
    __syncthreads();

    if (tid < 128) {
        int h = tid >> 4, t = tid & 15;
        const float* w = wq + h * MM;
        float acc = 0.f;
        for (int m = 0; m < MM; m += 2) {
            float2 v = __half22float2(*(const __half2*)&smv[t][m]);
            acc = fmaf(v.x, w[m], acc);
            acc = fmaf(v.y, w[m + 1], acc);
        }
        sw[h][t] = acc;
    }
    __syncthreads();
    if (tid < 8) {
        int h = tid;
        float mx = -1e30f;
        for (int t = 0; t < TT; t++) mx = fmaxf(mx, sw[h][t]);
        float s = 0.f;
        for (int t = 0; t < TT; t++) { float e = __expf(sw[h][t] - mx); ssm[h][t] = e; s += e; }
        float inv = 1.0f / s;
        for (int t = 0; t < TT; t++) ssm[h][t] *= inv;
    }
    __syncthreads();

    const float* gm = gmask + (size_t)n * MM;
    #pragma unroll
    for (int mm = 0; mm < 4; mm++) {
        int m = tid + mm * 256;
        int h = m >> 7;
        float acc = 0.f;
        #pragma unroll
        for (int t = 0; t < TT; t++) acc = fmaf(__half2float(smv[t][m]), ssm[h][t], acc);
        acc *= gm[m];
        mem_read[(size_t)n * MM + m] = __float2half(acc);
    }
}

// ---------------- LayerNorm + residual broadcast over T (one block per n) ----------------
__global__ __launch_bounds__(256)
void ln_add(const float* __restrict__ mem_out, const float* __restrict__ x,
            const float* __restrict__ gamma, const float* __restrict__ beta,
            const float* __restrict__ mmix, float* __restrict__ out)
{
    int n = blockIdx.x, tid = threadIdx.x;
    int lane = tid & 63, wave = tid >> 6;
    __shared__ float sred[10];
    float4 v = ((const float4*)(mem_out + (size_t)n * DD))[tid];
    float s  = v.x + v.y + v.z + v.w;
    float ss = v.x * v.x + v.y * v.y + v.z * v.z + v.w * v.w;
    #pragma unroll
    for (int o = 32; o > 0; o >>= 1) { s += __shfl_down(s, o, 64); ss += __shfl_down(ss, o, 64); }
    if (lane == 0) { sred[wave * 2] = s; sred[wave * 2 + 1] = ss; }
    __syncthreads();
    if (tid == 0) {
        float S = 0.f, SS = 0.f;
        for (int w = 0; w < 4; w++) { S += sred[w * 2]; SS += sred[w * 2 + 1]; }
        float mu = S * (1.0f / DD);
        float var = SS * (1.0f / DD) - mu * mu;
        sred[8] = mu;
        sred[9] = rsqrtf(var + 1e-5f);
    }
    __syncthreads();
    float mu = sred[8], rs = sred[9];
    float4 g = ((const float4*)gamma)[tid];
    float4 b = ((const float4*)beta)[tid];
    float4 nv;
    nv.x = (v.x - mu) * rs * g.x + b.x;
    nv.y = (v.y - mu) * rs * g.y + b.y;
    nv.z = (v.z - mu) * rs * g.z + b.z;
    nv.w = (v.w - mu) * rs * g.w + b.w;
    float mix = 1.0f / (1.0f + expf(-mmix[0]));
    for (int t = 0; t < TT; t++) {
        size_t off = ((size_t)t * NN + n) * DD;
        float4 xv = ((const float4*)(x + off))[tid];
        float4 o;
        o.x = xv.x + mix * nv.x;
        o.y = xv.y + mix * nv.y;
        o.z = xv.z + mix * nv.z;
        o.w = xv.w + mix * nv.w;
        ((float4*)(out + off))[tid] = o;
    }
}

__global__ void ws_sentinel(float* out) { out[0] = 12345.0f; }

extern "C" void kernel_launch(void* const* d_in, const int* in_sizes, int n_in,
                              void* d_out, int out_size, void* d_ws, size_t ws_size,
                              hipStream_t stream)
{
    const float* x     = (const float*)d_in[0];
    const float* Wto   = (const float*)d_in[1];
    const float* Wg    = (const float*)d_in[2];
    const float* Wrk   = (const float*)d_in[3];
    const float* Wfrom = (const float*)d_in[4];
    const float* q     = (const float*)d_in[5];
    const float* gthr  = (const float*)d_in[6];
    const float* gamma = (const float*)d_in[7];
    const float* beta  = (const float*)d_in[8];
    const float* mmix  = (const float*)d_in[9];
    float* out = (float*)d_out;

    char* w = (char*)d_ws;
    size_t off = 0;
    auto alloc = [&](size_t bytes) -> void* {
        void* p = w + off;
        off += (bytes + 255) & ~(size_t)255;
        return p;
    };
    __half* x_hi   = (__half*)alloc((size_t)ROWS * DD * 2);     // 64 MB
    __half* x_lo   = (__half*)alloc((size_t)ROWS * DD * 2);     // 64 MB
    __half* wc_hi  = (__half*)alloc((size_t)JJ * DD * 2);       // 4 MB
    __half* wc_lo  = (__half*)alloc((size_t)JJ * DD * 2);       // 4 MB
    __half* wf_hi  = (__half*)alloc((size_t)DD * MM * 2);       // 2 MB
    float*  wq     = (float*) alloc((size_t)HH * MM * 4);
    float*  mi_gi  = (float*) alloc((size_t)ROWS * JJ * 4);     // 256 MB
    __half* mv     = (__half*)alloc((size_t)TT * NN * MM * 2);  // 64 MB
    float*  gmask  = (float*) alloc((size_t)NN * MM * 4);       // 8 MB
    __half* m_read = (__half*)alloc((size_t)NN * MM * 2);       // 4 MB
    float*  m_out  = (float*) alloc((size_t)NN * DD * 4);       // 8 MB

    if (off > ws_size) {
        ws_sentinel<<<1, 1, 0, stream>>>(out);
        return;
    }

    // allow 128 KiB dynamic LDS for gemm8p (deterministic, capture-safe)
    hipFuncSetAttribute((const void*)gemm8p, hipFuncAttributeMaxDynamicSharedMemorySize, 131072);

    // 1) packs
    pack_hilo<<<(ROWS * DD / 4 + 255) / 256, 256, 0, stream>>>(x, x_hi, x_lo, ROWS * DD / 4);
    pack_hilo<<<(MM * DD / 4 + 255) / 256, 256, 0, stream>>>(Wto, wc_hi, wc_lo, MM * DD / 4);
    pack_hilo<<<(MM * DD / 4 + 255) / 256, 256, 0, stream>>>(Wg, wc_hi + (size_t)MM * DD, wc_lo + (size_t)MM * DD, MM * DD / 4);
    pack_hi<<<(DD * MM / 4 + 255) / 256, 256, 0, stream>>>(Wfrom, wf_hi, DD * MM / 4);
    compute_wq<<<dim3(4, 8), 256, 0, stream>>>(Wrk, q, wq);

    // 2) big 3-term f16 GEMM (triplet-reordered, T2-swizzled): mi|gi = x @ [W_to;W_gate]^T
    gemm8p<<<(ROWS / 256) * (JJ / 256), 512, 131072, stream>>>(x_hi, x_lo, wc_hi, wc_lo, mi_gi);

    // 3) LIF scan (mem + gate)
    lif_kernel<<<NN * MM / 256, 256, 0, stream>>>(mi_gi, mv, gmask, gthr);

    // 4) attention scores + softmax + gated mem_read
    attn_memread<<<NN, 256, 0, stream>>>(mv, wq, gmask, m_read);

    // 5) mem_out = mem_read @ W_from^T  (2048 x 1024, K=1024), single-term f16
    gemm_f16<1><<<(NN / 128) * (DD / 128), 256, 0, stream>>>(m_read, m_read, wf_hi, wf_hi, m_out, MM, DD, 3);

    // 6) LayerNorm + residual broadcast over T
    ln_add<<<NN, 256, 0, stream>>>(m_out, x, gamma, beta, mmix, out);
}

// Round 7
// 583.805 us; speedup vs baseline: 1.3596x; 1.0162x over previous
//
#include <hip/hip_runtime.h>
#include <hip/hip_bf16.h>
#include <hip/hip_fp16.h>

// Problem constants
#define TT 16
#define NN 2048          // B*S
#define DD 1024
#define MM 1024
#define HH 8
#define ROWS 32768       // T*N
#define JJ 2048          // 2*M (mi | gi packed)

typedef _Float16 f16x8 __attribute__((ext_vector_type(8)));
typedef float f32x4 __attribute__((ext_vector_type(4)));

#define SB  __builtin_amdgcn_sched_barrier(0)
#define BAR __builtin_amdgcn_s_barrier()

__device__ __forceinline__ void gload16(const void* g, void* l) {
    __builtin_amdgcn_global_load_lds((const __attribute__((address_space(1))) void*)g,
                                     (__attribute__((address_space(3))) void*)l, 16, 0, 0);
}

// ---------------- pack fp32 -> f16 hi only ----------------
__global__ __launch_bounds__(256) void pack_hi(const float* __restrict__ in,
                                               __half* __restrict__ hi, long n4) {
    long i = (long)blockIdx.x * 256 + threadIdx.x;
    if (i >= n4) return;
    float4 v = ((const float4*)in)[i];
    ushort4 H = { __half_as_ushort(__float2half(v.x)), __half_as_ushort(__float2half(v.y)),
                  __half_as_ushort(__float2half(v.z)), __half_as_ushort(__float2half(v.w)) };
    ((ushort4*)hi)[i] = H;
}

// ---------------- pack fp32 -> f16 hi/lo ----------------
__global__ __launch_bounds__(256) void pack_hilo(const float* __restrict__ in,
                                                 __half* __restrict__ hi,
                                                 __half* __restrict__ lo, long n4) {
    long i = (long)blockIdx.x * 256 + threadIdx.x;
    if (i >= n4) return;
    float4 v = ((const float4*)in)[i];
    __half h0 = __float2half(v.x), h1 = __float2half(v.y);
    __half h2 = __float2half(v.z), h3 = __float2half(v.w);
    __half l0 = __float2half(v.x - __half2float(h0));
    __half l1 = __float2half(v.y - __half2float(h1));
    __half l2 = __float2half(v.z - __half2float(h2));
    __half l3 = __float2half(v.w - __half2float(h3));
    ushort4 H = { __half_as_ushort(h0), __half_as_ushort(h1), __half_as_ushort(h2), __half_as_ushort(h3) };
    ushort4 L = { __half_as_ushort(l0), __half_as_ushort(l1), __half_as_ushort(l2), __half_as_ushort(l3) };
    ((ushort4*)hi)[i] = H;
    ((ushort4*)lo)[i] = L;
}

// ---------------- wq[h][m] = scale * sum_hd q[h,hd]*Wrk[h*128+hd, m] ----------------
__global__ __launch_bounds__(256) void compute_wq(const float* __restrict__ Wrk,
                                                  const float* __restrict__ q,
                                                  float* __restrict__ wq) {
    int m = blockIdx.x * 256 + threadIdx.x;   // 0..1023
    int h = blockIdx.y;                        // 0..7
    const float* qh = q + h * 128;
    const float* wr = Wrk + (size_t)h * 128 * MM + m;
    float acc = 0.f;
    for (int hd = 0; hd < 128; hd++) acc = fmaf(qh[hd], wr[(size_t)hd * MM], acc);
    wq[h * MM + m] = acc * 0.08838834764831845f;   // 1/sqrt(128)
}

// =============================================================================
// 256x256 3-term f16 GEMM, triplet-reordered {Ahi*Bh, Ahi*Bl, Alo*Bh},
// BARRIER-SLIM: ONE vmcnt(0)+s_barrier per triplet (was 12 barriers).
// Safety: within a triplet, all ds_reads hit parity p while all stages write
// parity pn -> no intra-triplet conflict. Cross-triplet: (1) reads of p need
// all waves' p-stages done = per-wave vmcnt(0) + barrier at triplet start;
// (2) stage(pn)@kt vs reads of pn@kt-1: any wave past the kt barrier already
// issued its kt-1 MFMAs, whose lgkmcnt waits consumed those reads.
// T2 XOR swizzle (slot p = j ^ ((row>>1)&3)) as R6: zero bank conflicts.
// =============================================================================
__global__ __launch_bounds__(512, 2)
void gemm8p(const __half* __restrict__ Ahi, const __half* __restrict__ Alo,
            const __half* __restrict__ Bhi, const __half* __restrict__ Blo,
            float* __restrict__ C)
{
    extern __shared__ __align__(16) char smem[];
    char* AHb = smem;                 // [2 parity][16384 B] each
    char* ALb = smem + 32768;
    char* BHb = smem + 65536;
    char* BLb = smem + 98304;

    const int tid = threadIdx.x, lane = tid & 63, wave = tid >> 6;
    const int l15 = lane & 15, l4 = lane >> 4;
    const int wm = wave >> 2, wn = wave & 3;

    // XCD-contiguous swizzle (1024 blocks), col-fastest within chunk.
    const int orig = blockIdx.x;
    const int wg   = (orig & 7) * 128 + (orig >> 3);
    const int rb   = (wg >> 3) * 256;
    const int cb   = (wg & 7) * 256;

    // Stage 8KB slice s of a 16KB tile (256 rows x 64B = BK 32 f16).
    // Linear LDS dest; global source slot inverse-permuted by the swizzle.
    auto stageU = [&](const __half* src, int row0, char* dstbase, int par, int kt, int s) {
        int t   = s * 512 + tid;            // 16B chunk 0..1023
        int row = t >> 2;
        int p   = t & 3;                    // physical slot in row
        int kb  = (p ^ ((row >> 1) & 3)) * 16;   // source k-slot bytes
        const char* g = (const char*)(src + (size_t)(row0 + row) * 1024 + kt * 32) + kb;
        gload16(g, dstbase + par * 16384 + (size_t)(s * 512 + wave * 64) * 16);
    };
    // Swizzled read: k-slot l4 lives at physical slot l4 ^ ((row>>1)&3).
    auto rdT = [&](const char* base, int par, int row) -> f16x8 {
        int p = l4 ^ ((row >> 1) & 3);
        return *(const f16x8*)(base + par * 16384 + row * 64 + p * 16);
    };

    f32x4 acc[8][4] = {};
    const int NKT = 32;                     // k0 triplets

    // Prologue: stage triplet 0 (parity 0), 8 loads/thread.
    stageU(Ahi, rb, AHb, 0, 0, 0); stageU(Ahi, rb, AHb, 0, 0, 1);
    stageU(Alo, rb, ALb, 0, 0, 0); stageU(Alo, rb, ALb, 0, 0, 1);
    stageU(Bhi, cb, BHb, 0, 0, 0); stageU(Bhi, cb, BHb, 0, 0, 1);
    stageU(Blo, cb, BLb, 0, 0, 0); stageU(Blo, cb, BLb, 0, 0, 1);

    for (int kt = 0; kt < NKT; kt++) {
        const int p = kt & 1, pn = p ^ 1;
        const bool pre = (kt + 1 < NKT);
        f16x8 a[8], bh[4], bl[4];

        // ---- triplet-start sync: parity-p tiles all present across waves
        asm volatile("s_waitcnt vmcnt(0)" ::: "memory");
        SB; BAR;

        // reads (parity p) + prefetch stages (parity pn) + 96 MFMA, free-scheduled
        #pragma unroll
        for (int i = 0; i < 8; i++) a[i] = rdT(AHb, p, wm * 128 + i * 16 + l15);
        #pragma unroll
        for (int n = 0; n < 4; n++) bh[n] = rdT(BHb, p, wn * 64 + n * 16 + l15);
        if (pre) {
            stageU(Ahi, rb, AHb, pn, kt + 1, 0); stageU(Ahi, rb, AHb, pn, kt + 1, 1);
            stageU(Alo, rb, ALb, pn, kt + 1, 0); stageU(Alo, rb, ALb, pn, kt + 1, 1);
        }
        __builtin_amdgcn_s_setprio(1);
        #pragma unroll
        for (int i = 0; i < 8; i++)
            #pragma unroll
            for (int n = 0; n < 4; n++)
                acc[i][n] = __builtin_amdgcn_mfma_f32_16x16x32_f16(a[i], bh[n], acc[i][n], 0, 0, 0);
        __builtin_amdgcn_s_setprio(0);

        #pragma unroll
        for (int n = 0; n < 4; n++) bl[n] = rdT(BLb, p, wn * 64 + n * 16 + l15);
        if (pre) {
            stageU(Bhi, cb, BHb, pn, kt + 1, 0); stageU(Bhi, cb, BHb, pn, kt + 1, 1);
            stageU(Blo, cb, BLb, pn, kt + 1, 0); stageU(Blo, cb, BLb, pn, kt + 1, 1);
        }
        __builtin_amdgcn_s_setprio(1);
        #pragma unroll
        for (int i = 0; i < 8; i++)
            #pragma unroll
            for (int n = 0; n < 4; n++)
                acc[i][n] = __builtin_amdgcn_mfma_f32_16x16x32_f16(a[i], bl[n], acc[i][n], 0, 0, 0);
        __builtin_amdgcn_s_setprio(0);

        #pragma unroll
        for (int i = 0; i < 8; i++) a[i] = rdT(ALb, p, wm * 128 + i * 16 + l15);
        __builtin_amdgcn_s_setprio(1);
        #pragma unroll
        for (int i = 0; i < 8; i++)
            #pragma unroll
            for (int n = 0; n < 4; n++)
                acc[i][n] = __builtin_amdgcn_mfma_f32_16x16x32_f16(a[i], bh[n], acc[i][n], 0, 0, 0);
        __builtin_amdgcn_s_setprio(0);
    }

    // epilogue: C/D layout (HW-verified): col = lane&15, row = 4*(lane>>4)+reg
    #pragma unroll
    for (int i = 0; i < 8; i++) {
        int r0 = rb + wm * 128 + i * 16 + l4 * 4;
        #pragma unroll
        for (int nf = 0; nf < 4; nf++) {
            int c = cb + wn * 64 + nf * 16 + l15;
            #pragma unroll
            for (int reg = 0; reg < 4; reg++)
                C[(size_t)(r0 + reg) * JJ + c] = acc[i][nf][reg];
        }
    }
}

// ---------------- 128x128 f16 GEMM (kept for the small projection) ----------------
template<int TERMS>
__global__ __launch_bounds__(256, 2)
void gemm_f16(const __half* __restrict__ Ahi, const __half* __restrict__ Alo,
              const __half* __restrict__ Bhi, const __half* __restrict__ Blo,
              float* __restrict__ C, int K, int ldc, int ncb_log2)
{
    __shared__ __align__(16) __half lds[2][4][8][512];
    const int tid  = threadIdx.x;
    const int lane = tid & 63;
    const int wave = tid >> 6;
    const int l15  = lane & 15, l4 = lane >> 4;

    const int nwg  = gridDim.x;
    const int orig = blockIdx.x;
    const int wg   = (orig & 7) * (nwg >> 3) + (orig >> 3);
    const int rb = (wg >> ncb_log2) * 128;
    const int cb = (wg & ((1 << ncb_log2) - 1)) * 128;

    auto stage = [&](int buf, int ks) {
        const int k0 = ks * 32;
        #pragma unroll
        for (int qq = 0; qq < 2; qq++) {
            int g = wave * 2 + qq;
            size_t aoff = (size_t)(rb + g * 16 + l15) * K + (k0 + 8 * l4);
            gload16(Ahi + aoff, &lds[buf][0][g][0]);
            if constexpr (TERMS == 3) gload16(Alo + aoff, &lds[buf][1][g][0]);
            size_t boff = (size_t)(cb + g * 16 + l15) * K + (k0 + 8 * l4);
            gload16(Bhi + boff, &lds[buf][2][g][0]);
            if constexpr (TERMS == 3) gload16(Blo + boff, &lds[buf][3][g][0]);
        }
    };

    const int wave_r = (wave >> 1) * 64;
    const int wave_c = (wave & 1) * 64;
    const int ag0 = wave_r >> 4;
    const int bg0 = wave_c >> 4;

    f32x4 acc[4][4] = {};
    const int nks = K >> 5;
    stage(0, 0);
    int buf = 0;
    for (int ks = 0; ks < nks; ks++) {
        __syncthreads();
        if (ks + 1 < nks) stage(buf ^ 1, ks + 1);
        f16x8 ah[4], bh[4], al[4], bl[4];
        #pragma unroll
        for (int i = 0; i < 4; i++) {
            ah[i] = *(const f16x8*)&lds[buf][0][ag0 + i][lane * 8];
            bh[i] = *(const f16x8*)&lds[buf][2][bg0 + i][lane * 8];
            if constexpr (TERMS == 3) {
                al[i] = *(const f16x8*)&lds[buf][1][ag0 + i][lane * 8];
                bl[i] = *(const f16x8*)&lds[buf][3][bg0 + i][lane * 8];
            }
        }
        #pragma unroll
        for (int m = 0; m < 4; m++)
            #pragma unroll
            for (int n = 0; n < 4; n++) {
                acc[m][n] = __builtin_amdgcn_mfma_f32_16x16x32_f16(ah[m], bh[n], acc[m][n], 0, 0, 0);
                if constexpr (TERMS == 3) {
                    acc[m][n] = __builtin_amdgcn_mfma_f32_16x16x32_f16(ah[m], bl[n], acc[m][n], 0, 0, 0);
                    acc[m][n] = __builtin_amdgcn_mfma_f32_16x16x32_f16(al[m], bh[n], acc[m][n], 0, 0, 0);
                }
            }
        buf ^= 1;
    }
    #pragma unroll
    for (int m = 0; m < 4; m++)
        #pragma unroll
        for (int n = 0; n < 4; n++) {
            int r0 = rb + wave_r + m * 16 + l4 * 4;
            int c  = cb + wave_c + n * 16 + l15;
            #pragma unroll
            for (int reg = 0; reg < 4; reg++)
                C[(size_t)(r0 + reg) * ldc + c] = acc[m][n][reg];
        }
}

// ---------------- LIF over T for mem + gate paths ----------------
__global__ __launch_bounds__(256)
void lif_kernel(const float* __restrict__ mi_gi, __half* __restrict__ mv,
                float* __restrict__ gmask, const float* __restrict__ gate_thr)
{
    int idx = blockIdx.x * 256 + threadIdx.x;   // n*1024 + m
    int n = idx >> 10, m = idx & 1023;
    const float* pm = mi_gi + (size_t)n * JJ + m;
    const size_t tstride = (size_t)NN * JJ;
    __half* pv = mv + idx;
    float vm = 0.f, vg = 0.f, cnt = 0.f;
    #pragma unroll
    for (int t = 0; t < TT; t++) {
        float im = pm[(size_t)t * tstride];
        vm = 0.99f * vm + im;
        pv[(size_t)t * (NN * MM)] = __float2half(vm);   // pre-reset trace
        if (vm >= 1.0f) vm -= 1.0f;
        float ig = pm[(size_t)t * tstride + MM];
        vg = 0.9f * vg + ig;
        if (vg >= 1.0f) { vg -= 1.0f; cnt += 1.0f; }
    }
    float gs = cnt * 0.0625f;
    gmask[idx] = 1.0f / (1.0f + expf(-10.0f * (gs - gate_thr[0])));
}

// ---------------- attention scores + softmax + mem_read (one block per n) ----------------
__global__ __launch_bounds__(256)
void attn_memread(const __half* __restrict__ mv, const float* __restrict__ wq,
                  const float* __restrict__ gmask, __half* __restrict__ mem_read)
{
    int n = blockIdx.x;
    __shared__ __align__(16) __half smv[TT][1032];
    __shared__ float sw[HH][TT];
    __shared__ float ssm[HH][TT];
    int tid = threadIdx.x;

    for (int t = 0; t < TT; t++) {
        const ushort4* src = (const ushort4*)(mv + ((size_t)t * NN + n) * MM);
        ((ushort4*)&smv[t][0])[tid] = src[tid];
    }
    __syncthreads();

    if (tid < 128) {
        int h = tid >> 4, t = tid & 15;
        const float* w = wq + h * MM;
        float acc = 0.f;
        for (int m = 0; m < MM; m += 2) {
            float2 v = __half22float2(*(const __half2*)&smv[t][m]);
            acc = fmaf(v.x, w[m], acc);
            acc = fmaf(v.y, w[m + 1], acc);
        }
        sw[h][t] = acc;
    }
    __syncthreads();
    if (tid < 8) {
        int h = tid;
        float mx = -1e30f;
        for (int t = 0; t < TT; t++) mx = fmaxf(mx, sw[h][t]);
        float s = 0.f;
        for (int t = 0; t < TT; t++) { float e = __expf(sw[h][t] - mx); ssm[h][t] = e; s += e; }
        float inv = 1.0f / s;
        for (int t = 0; t < TT; t++) ssm[h][t] *= inv;
    }
    __syncthreads();

    const float* gm = gmask + (size_t)n * MM;
    #pragma unroll
    for (int mm = 0; mm < 4; mm++) {
        int m = tid + mm * 256;
        int h = m >> 7;
        float acc = 0.f;
        #pragma unroll
        for (int t = 0; t < TT; t++) acc = fmaf(__half2float(smv[t][m]), ssm[h][t], acc);
        acc *= gm[m];
        mem_read[(size_t)n * MM + m] = __float2half(acc);
    }
}

// ---------------- LayerNorm + residual broadcast over T (one block per n) ----------------
__global__ __launch_bounds__(256)
void ln_add(const float* __restrict__ mem_out, const float* __restrict__ x,
            const float* __restrict__ gamma, const float* __restrict__ beta,
            const float* __restrict__ mmix, float* __restrict__ out)
{
    int n = blockIdx.x, tid = threadIdx.x;
    int lane = tid & 63, wave = tid >> 6;
    __shared__ float sred[10];
    float4 v = ((const float4*)(mem_out + (size_t)n * DD))[tid];
    float s  = v.x + v.y + v.z + v.w;
    float ss = v.x * v.x + v.y * v.y + v.z * v.z + v.w * v.w;
    #pragma unroll
    for (int o = 32; o > 0; o >>= 1) { s += __shfl_down(s, o, 64); ss += __shfl_down(ss, o, 64); }
    if (lane == 0) { sred[wave * 2] = s; sred[wave * 2 + 1] = ss; }
    __syncthreads();
    if (tid == 0) {
        float S = 0.f, SS = 0.f;
        for (int w = 0; w < 4; w++) { S += sred[w * 2]; SS += sred[w * 2 + 1]; }
        float mu = S * (1.0f / DD);
        float var = SS * (1.0f / DD) - mu * mu;
        sred[8] = mu;
        sred[9] = rsqrtf(var + 1e-5f);
    }
    __syncthreads();
    float mu = sred[8], rs = sred[9];
    float4 g = ((const float4*)gamma)[tid];
    float4 b = ((const float4*)beta)[tid];
    float4 nv;
    nv.x = (v.x - mu) * rs * g.x + b.x;
    nv.y = (v.y - mu) * rs * g.y + b.y;
    nv.z = (v.z - mu) * rs * g.z + b.z;
    nv.w = (v.w - mu) * rs * g.w + b.w;
    float mix = 1.0f / (1.0f + expf(-mmix[0]));
    for (int t = 0; t < TT; t++) {
        size_t off = ((size_t)t * NN + n) * DD;
        float4 xv = ((const float4*)(x + off))[tid];
        float4 o;
        o.x = xv.x + mix * nv.x;
        o.y = xv.y + mix * nv.y;
        o.z = xv.z + mix * nv.z;
        o.w = xv.w + mix * nv.w;
        ((float4*)(out + off))[tid] = o;
    }
}

__global__ void ws_sentinel(float* out) { out[0] = 12345.0f; }

extern "C" void kernel_launch(void* const* d_in, const int* in_sizes, int n_in,
                              void* d_out, int out_size, void* d_ws, size_t ws_size,
                              hipStream_t stream)
{
    const float* x     = (const float*)d_in[0];
    const float* Wto   = (const float*)d_in[1];
    const float* Wg    = (const float*)d_in[2];
    const float* Wrk   = (const float*)d_in[3];
    const float* Wfrom = (const float*)d_in[4];
    const float* q     = (const float*)d_in[5];
    const float* gthr  = (const float*)d_in[6];
    const float* gamma = (const float*)d_in[7];
    const float* beta  = (const float*)d_in[8];
    const float* mmix  = (const float*)d_in[9];
    float* out = (float*)d_out;

    char* w = (char*)d_ws;
    size_t off = 0;
    auto alloc = [&](size_t bytes) -> void* {
        void* p = w + off;
        off += (bytes + 255) & ~(size_t)255;
        return p;
    };
    __half* x_hi   = (__half*)alloc((size_t)ROWS * DD * 2);     // 64 MB
    __half* x_lo   = (__half*)alloc((size_t)ROWS * DD * 2);     // 64 MB
    __half* wc_hi  = (__half*)alloc((size_t)JJ * DD * 2);       // 4 MB
    __half* wc_lo  = (__half*)alloc((size_t)JJ * DD * 2);       // 4 MB
    __half* wf_hi  = (__half*)alloc((size_t)DD * MM * 2);       // 2 MB
    float*  wq     = (float*) alloc((size_t)HH * MM * 4);
    float*  mi_gi  = (float*) alloc((size_t)ROWS * JJ * 4);     // 256 MB
    __half* mv     = (__half*)alloc((size_t)TT * NN * MM * 2);  // 64 MB
    float*  gmask  = (float*) alloc((size_t)NN * MM * 4);       // 8 MB
    __half* m_read = (__half*)alloc((size_t)NN * MM * 2);       // 4 MB
    float*  m_out  = (float*) alloc((size_t)NN * DD * 4);       // 8 MB

    if (off > ws_size) {
        ws_sentinel<<<1, 1, 0, stream>>>(out);
        return;
    }

    // allow 128 KiB dynamic LDS for gemm8p (deterministic, capture-safe)
    hipFuncSetAttribute((const void*)gemm8p, hipFuncAttributeMaxDynamicSharedMemorySize, 131072);

    // 1) packs
    pack_hilo<<<(ROWS * DD / 4 + 255) / 256, 256, 0, stream>>>(x, x_hi, x_lo, ROWS * DD / 4);
    pack_hilo<<<(MM * DD / 4 + 255) / 256, 256, 0, stream>>>(Wto, wc_hi, wc_lo, MM * DD / 4);
    pack_hilo<<<(MM * DD / 4 + 255) / 256, 256, 0, stream>>>(Wg, wc_hi + (size_t)MM * DD, wc_lo + (size_t)MM * DD, MM * DD / 4);
    pack_hi<<<(DD * MM / 4 + 255) / 256, 256, 0, stream>>>(Wfrom, wf_hi, DD * MM / 4);
    compute_wq<<<dim3(4, 8), 256, 0, stream>>>(Wrk, q, wq);

    // 2) big 3-term f16 GEMM (triplet-reordered, T2-swizzled, barrier-slim)
    gemm8p<<<(ROWS / 256) * (JJ / 256), 512, 131072, stream>>>(x_hi, x_lo, wc_hi, wc_lo, mi_gi);

    // 3) LIF scan (mem + gate)
    lif_kernel<<<NN * MM / 256, 256, 0, stream>>>(mi_gi, mv, gmask, gthr);

    // 4) attention scores + softmax + gated mem_read
    attn_memread<<<NN, 256, 0, stream>>>(mv, wq, gmask, m_read);

    // 5) mem_out = mem_read @ W_from^T  (2048 x 1024, K=1024), single-term f16
    gemm_f16<1><<<(NN / 128) * (DD / 128), 256, 0, stream>>>(m_read, m_read, wf_hi, wf_hi, m_out, MM, DD, 3);

    // 6) LayerNorm + residual broadcast over T
    ln_add<<<NN, 256, 0, stream>>>(m_out, x, gamma, beta, mmix, out);
}

// Round 8
// 505.977 us; speedup vs baseline: 1.5688x; 1.1538x over previous
//
#include <hip/hip_runtime.h>
#include <hip/hip_bf16.h>
#include <hip/hip_fp16.h>

// Problem constants
#define TT 16
#define NN 2048          // B*S
#define DD 1024
#define MM 1024
#define HH 8
#define ROWS 32768       // T*N
#define JJ 2048          // 2*M (mi | gi packed)

typedef _Float16 f16x8 __attribute__((ext_vector_type(8)));
typedef float f32x4 __attribute__((ext_vector_type(4)));

#define SB  __builtin_amdgcn_sched_barrier(0)
#define BAR __builtin_amdgcn_s_barrier()

__device__ __forceinline__ void gload16(const void* g, void* l) {
    __builtin_amdgcn_global_load_lds((const __attribute__((address_space(1))) void*)g,
                                     (__attribute__((address_space(3))) void*)l, 16, 0, 0);
}

// ---------------- pack fp32 -> f16 hi only ----------------
__global__ __launch_bounds__(256) void pack_hi(const float* __restrict__ in,
                                               __half* __restrict__ hi, long n4) {
    long i = (long)blockIdx.x * 256 + threadIdx.x;
    if (i >= n4) return;
    float4 v = ((const float4*)in)[i];
    ushort4 H = { __half_as_ushort(__float2half(v.x)), __half_as_ushort(__float2half(v.y)),
                  __half_as_ushort(__float2half(v.z)), __half_as_ushort(__float2half(v.w)) };
    ((ushort4*)hi)[i] = H;
}

// ---------------- pack fp32 -> f16 hi/lo ----------------
__global__ __launch_bounds__(256) void pack_hilo(const float* __restrict__ in,
                                                 __half* __restrict__ hi,
                                                 __half* __restrict__ lo, long n4) {
    long i = (long)blockIdx.x * 256 + threadIdx.x;
    if (i >= n4) return;
    float4 v = ((const float4*)in)[i];
    __half h0 = __float2half(v.x), h1 = __float2half(v.y);
    __half h2 = __float2half(v.z), h3 = __float2half(v.w);
    __half l0 = __float2half(v.x - __half2float(h0));
    __half l1 = __float2half(v.y - __half2float(h1));
    __half l2 = __float2half(v.z - __half2float(h2));
    __half l3 = __float2half(v.w - __half2float(h3));
    ushort4 H = { __half_as_ushort(h0), __half_as_ushort(h1), __half_as_ushort(h2), __half_as_ushort(h3) };
    ushort4 L = { __half_as_ushort(l0), __half_as_ushort(l1), __half_as_ushort(l2), __half_as_ushort(l3) };
    ((ushort4*)hi)[i] = H;
    ((ushort4*)lo)[i] = L;
}

// ---- pack x fp32 -> f16 hi/lo with bit-interleaved row permutation ----
// packed row r bits (within 256-row tile): [n3 n2 t3 t2 n1 n0 t1 t0]
// so that each lane's acc registers hold 2 full (n, all-16-t) LIF scans.
__global__ __launch_bounds__(256) void pack_hilo_perm(const float* __restrict__ in,
                                                      __half* __restrict__ hi,
                                                      __half* __restrict__ lo) {
    long i = (long)blockIdx.x * 256 + threadIdx.x;   // float4 index over output
    int R   = (int)(i >> 8);       // packed row 0..32767
    int d4  = (int)(i & 255);      // float4 within row
    int r   = R & 255, blk = R >> 8;
    int n_l = ((r >> 7) & 1) * 8 + ((r >> 6) & 1) * 4 + ((r >> 2) & 3);
    int t   = ((r >> 4) & 3) * 4 + (r & 3);
    int n_g = blk * 16 + n_l;
    long src = ((long)t * NN + n_g) * 256 + d4;      // D/4 = 256 float4 per row
    float4 v = ((const float4*)in)[src];
    __half h0 = __float2half(v.x), h1 = __float2half(v.y);
    __half h2 = __float2half(v.z), h3 = __float2half(v.w);
    __half l0 = __float2half(v.x - __half2float(h0));
    __half l1 = __float2half(v.y - __half2float(h1));
    __half l2 = __float2half(v.z - __half2float(h2));
    __half l3 = __float2half(v.w - __half2float(h3));
    ushort4 H = { __half_as_ushort(h0), __half_as_ushort(h1), __half_as_ushort(h2), __half_as_ushort(h3) };
    ushort4 L = { __half_as_ushort(l0), __half_as_ushort(l1), __half_as_ushort(l2), __half_as_ushort(l3) };
    ((ushort4*)hi)[i] = H;
    ((ushort4*)lo)[i] = L;
}

// ---------------- wq[h][m] = scale * sum_hd q[h,hd]*Wrk[h*128+hd, m] ----------------
__global__ __launch_bounds__(256) void compute_wq(const float* __restrict__ Wrk,
                                                  const float* __restrict__ q,
                                                  float* __restrict__ wq) {
    int m = blockIdx.x * 256 + threadIdx.x;   // 0..1023
    int h = blockIdx.y;                        // 0..7
    const float* qh = q + h * 128;
    const float* wr = Wrk + (size_t)h * 128 * MM + m;
    float acc = 0.f;
    for (int hd = 0; hd < 128; hd++) acc = fmaf(qh[hd], wr[(size_t)hd * MM], acc);
    wq[h * MM + m] = acc * 0.08838834764831845f;   // 1/sqrt(128)
}

// =============================================================================
// 256x256 3-term f16 GEMM (triplet {Ahi*Bh, Ahi*Bl, Alo*Bh}, barrier-slim,
// T2 XOR swizzle) + FUSED LIF EPILOGUE.
// A rows are bit-interleave-permuted (pack_hilo_perm) so each lane's acc holds
// 2 complete (n, 16-t) scans in-register: n_l = wm*8+i2*4+l4, t = tt*4+reg,
// acc index i = i2*4+tt. mi blocks (cb<1024): tau=.99, stage pre-reset traces
// in LDS (free after K-loop) as f16 [16t][16n][256m], vector-store to mv.
// gi blocks: tau=.9, spike count -> gmask directly. mi_gi buffer eliminated.
// =============================================================================
__global__ __launch_bounds__(512, 2)
void gemm8p(const __half* __restrict__ Ahi, const __half* __restrict__ Alo,
            const __half* __restrict__ Bhi, const __half* __restrict__ Blo,
            __half* __restrict__ mv, float* __restrict__ gmask,
            const float* __restrict__ gate_thr)
{
    extern __shared__ __align__(16) char smem[];
    char* AHb = smem;                 // [2 parity][16384 B] each
    char* ALb = smem + 32768;
    char* BHb = smem + 65536;
    char* BLb = smem + 98304;

    const int tid = threadIdx.x, lane = tid & 63, wave = tid >> 6;
    const int l15 = lane & 15, l4 = lane >> 4;
    const int wm = wave >> 2, wn = wave & 3;

    // XCD-contiguous swizzle (1024 blocks), col-fastest within chunk.
    const int orig = blockIdx.x;
    const int wg   = (orig & 7) * 128 + (orig >> 3);
    const int rb   = (wg >> 3) * 256;
    const int cb   = (wg & 7) * 256;

    auto stageU = [&](const __half* src, int row0, char* dstbase, int par, int kt, int s) {
        int t   = s * 512 + tid;            // 16B chunk 0..1023
        int row = t >> 2;
        int p   = t & 3;                    // physical slot in row
        int kb  = (p ^ ((row >> 1) & 3)) * 16;   // source k-slot bytes
        const char* g = (const char*)(src + (size_t)(row0 + row) * 1024 + kt * 32) + kb;
        gload16(g, dstbase + par * 16384 + (size_t)(s * 512 + wave * 64) * 16);
    };
    auto rdT = [&](const char* base, int par, int row) -> f16x8 {
        int p = l4 ^ ((row >> 1) & 3);
        return *(const f16x8*)(base + par * 16384 + row * 64 + p * 16);
    };

    f32x4 acc[8][4] = {};
    const int NKT = 32;                     // k0 triplets

    // Prologue: stage triplet 0 (parity 0), 8 loads/thread.
    stageU(Ahi, rb, AHb, 0, 0, 0); stageU(Ahi, rb, AHb, 0, 0, 1);
    stageU(Alo, rb, ALb, 0, 0, 0); stageU(Alo, rb, ALb, 0, 0, 1);
    stageU(Bhi, cb, BHb, 0, 0, 0); stageU(Bhi, cb, BHb, 0, 0, 1);
    stageU(Blo, cb, BLb, 0, 0, 0); stageU(Blo, cb, BLb, 0, 0, 1);

    for (int kt = 0; kt < NKT; kt++) {
        const int p = kt & 1, pn = p ^ 1;
        const bool pre = (kt + 1 < NKT);
        f16x8 a[8], bh[4], bl[4];

        // ---- triplet-start sync: parity-p tiles all present across waves
        asm volatile("s_waitcnt vmcnt(0)" ::: "memory");
        SB; BAR;

        #pragma unroll
        for (int i = 0; i < 8; i++) a[i] = rdT(AHb, p, wm * 128 + i * 16 + l15);
        #pragma unroll
        for (int n = 0; n < 4; n++) bh[n] = rdT(BHb, p, wn * 64 + n * 16 + l15);
        if (pre) {
            stageU(Ahi, rb, AHb, pn, kt + 1, 0); stageU(Ahi, rb, AHb, pn, kt + 1, 1);
            stageU(Alo, rb, ALb, pn, kt + 1, 0); stageU(Alo, rb, ALb, pn, kt + 1, 1);
        }
        __builtin_amdgcn_s_setprio(1);
        #pragma unroll
        for (int i = 0; i < 8; i++)
            #pragma unroll
            for (int n = 0; n < 4; n++)
                acc[i][n] = __builtin_amdgcn_mfma_f32_16x16x32_f16(a[i], bh[n], acc[i][n], 0, 0, 0);
        __builtin_amdgcn_s_setprio(0);

        #pragma unroll
        for (int n = 0; n < 4; n++) bl[n] = rdT(BLb, p, wn * 64 + n * 16 + l15);
        if (pre) {
            stageU(Bhi, cb, BHb, pn, kt + 1, 0); stageU(Bhi, cb, BHb, pn, kt + 1, 1);
            stageU(Blo, cb, BLb, pn, kt + 1, 0); stageU(Blo, cb, BLb, pn, kt + 1, 1);
        }
        __builtin_amdgcn_s_setprio(1);
        #pragma unroll
        for (int i = 0; i < 8; i++)
            #pragma unroll
            for (int n = 0; n < 4; n++)
                acc[i][n] = __builtin_amdgcn_mfma_f32_16x16x32_f16(a[i], bl[n], acc[i][n], 0, 0, 0);
        __builtin_amdgcn_s_setprio(0);

        #pragma unroll
        for (int i = 0; i < 8; i++) a[i] = rdT(ALb, p, wm * 128 + i * 16 + l15);
        __builtin_amdgcn_s_setprio(1);
        #pragma unroll
        for (int i = 0; i < 8; i++)
            #pragma unroll
            for (int n = 0; n < 4; n++)
                acc[i][n] = __builtin_amdgcn_mfma_f32_16x16x32_f16(a[i], bh[n], acc[i][n], 0, 0, 0);
        __builtin_amdgcn_s_setprio(0);
    }

    // ===== fused LIF epilogue =====
    // all waves must be fully done reading LDS before we reuse it
    asm volatile("s_waitcnt lgkmcnt(0) vmcnt(0)" ::: "memory");
    SB; BAR;

    const int n_g_base = rb >> 4;       // 16 n per block
    if (cb < 1024) {
        // memory path: tau=0.99, pre-reset trace -> LDS [16t][16n][256m] f16 -> mv
        __half* mvs = (__half*)smem;
        #pragma unroll
        for (int i2 = 0; i2 < 2; i2++) {
            int n_l = wm * 8 + i2 * 4 + l4;
            #pragma unroll
            for (int nf = 0; nf < 4; nf++) {
                int col = wn * 64 + nf * 16 + l15;
                float v = 0.f;
                #pragma unroll
                for (int tt = 0; tt < 4; tt++)
                    #pragma unroll
                    for (int reg = 0; reg < 4; reg++) {
                        int t = tt * 4 + reg;
                        v = 0.99f * v + acc[i2 * 4 + tt][nf][reg];
                        mvs[(t * 16 + n_l) * 256 + col] = __float2half(v);
                        if (v >= 1.0f) v -= 1.0f;
                    }
            }
        }
        SB; BAR;
        // cooperative vector store: 8192 x 16B chunks
        #pragma unroll
        for (int j = 0; j < 16; j++) {
            int k = j * 512 + tid;
            int e = k * 8;
            int t   = e >> 12;
            int n_l = (e >> 8) & 15;
            int m   = e & 255;
            float4 val = *(const float4*)((const char*)smem + (size_t)k * 16);
            *(float4*)(mv + ((size_t)(t * NN + n_g_base + n_l) * MM + cb + m)) = val;
        }
    } else {
        // gate path: tau=0.9, spike count -> gmask
        float thr = gate_thr[0];
        #pragma unroll
        for (int i2 = 0; i2 < 2; i2++) {
            int n_l = wm * 8 + i2 * 4 + l4;
            #pragma unroll
            for (int nf = 0; nf < 4; nf++) {
                int col = wn * 64 + nf * 16 + l15;
                float v = 0.f, cnt = 0.f;
                #pragma unroll
                for (int tt = 0; tt < 4; tt++)
                    #pragma unroll
                    for (int reg = 0; reg < 4; reg++) {
                        v = 0.9f * v + acc[i2 * 4 + tt][nf][reg];
                        if (v >= 1.0f) { v -= 1.0f; cnt += 1.0f; }
                    }
                float gs = cnt * 0.0625f;
                gmask[(size_t)(n_g_base + n_l) * MM + (cb - 1024) + col] =
                    1.0f / (1.0f + expf(-10.0f * (gs - thr)));
            }
        }
    }
}

// ---------------- 128x128 f16 GEMM (kept for the small projection) ----------------
template<int TERMS>
__global__ __launch_bounds__(256, 2)
void gemm_f16(const __half* __restrict__ Ahi, const __half* __restrict__ Alo,
              const __half* __restrict__ Bhi, const __half* __restrict__ Blo,
              float* __restrict__ C, int K, int ldc, int ncb_log2)
{
    __shared__ __align__(16) __half lds[2][4][8][512];
    const int tid  = threadIdx.x;
    const int lane = tid & 63;
    const int wave = tid >> 6;
    const int l15  = lane & 15, l4 = lane >> 4;

    const int nwg  = gridDim.x;
    const int orig = blockIdx.x;
    const int wg   = (orig & 7) * (nwg >> 3) + (orig >> 3);
    const int rb = (wg >> ncb_log2) * 128;
    const int cb = (wg & ((1 << ncb_log2) - 1)) * 128;

    auto stage = [&](int buf, int ks) {
        const int k0 = ks * 32;
        #pragma unroll
        for (int qq = 0; qq < 2; qq++) {
            int g = wave * 2 + qq;
            size_t aoff = (size_t)(rb + g * 16 + l15) * K + (k0 + 8 * l4);
            gload16(Ahi + aoff, &lds[buf][0][g][0]);
            if constexpr (TERMS == 3) gload16(Alo + aoff, &lds[buf][1][g][0]);
            size_t boff = (size_t)(cb + g * 16 + l15) * K + (k0 + 8 * l4);
            gload16(Bhi + boff, &lds[buf][2][g][0]);
            if constexpr (TERMS == 3) gload16(Blo + boff, &lds[buf][3][g][0]);
        }
    };

    const int wave_r = (wave >> 1) * 64;
    const int wave_c = (wave & 1) * 64;
    const int ag0 = wave_r >> 4;
    const int bg0 = wave_c >> 4;

    f32x4 acc[4][4] = {};
    const int nks = K >> 5;
    stage(0, 0);
    int buf = 0;
    for (int ks = 0; ks < nks; ks++) {
        __syncthreads();
        if (ks + 1 < nks) stage(buf ^ 1, ks + 1);
        f16x8 ah[4], bh[4], al[4], bl[4];
        #pragma unroll
        for (int i = 0; i < 4; i++) {
            ah[i] = *(const f16x8*)&lds[buf][0][ag0 + i][lane * 8];
            bh[i] = *(const f16x8*)&lds[buf][2][bg0 + i][lane * 8];
            if constexpr (TERMS == 3) {
                al[i] = *(const f16x8*)&lds[buf][1][ag0 + i][lane * 8];
                bl[i] = *(const f16x8*)&lds[buf][3][bg0 + i][lane * 8];
            }
        }
        #pragma unroll
        for (int m = 0; m < 4; m++)
            #pragma unroll
            for (int n = 0; n < 4; n++) {
                acc[m][n] = __builtin_amdgcn_mfma_f32_16x16x32_f16(ah[m], bh[n], acc[m][n], 0, 0, 0);
                if constexpr (TERMS == 3) {
                    acc[m][n] = __builtin_amdgcn_mfma_f32_16x16x32_f16(ah[m], bl[n], acc[m][n], 0, 0, 0);
                    acc[m][n] = __builtin_amdgcn_mfma_f32_16x16x32_f16(al[m], bh[n], acc[m][n], 0, 0, 0);
                }
            }
        buf ^= 1;
    }
    #pragma unroll
    for (int m = 0; m < 4; m++)
        #pragma unroll
        for (int n = 0; n < 4; n++) {
            int r0 = rb + wave_r + m * 16 + l4 * 4;
            int c  = cb + wave_c + n * 16 + l15;
            #pragma unroll
            for (int reg = 0; reg < 4; reg++)
                C[(size_t)(r0 + reg) * ldc + c] = acc[m][n][reg];
        }
}

// ---------------- attention scores + softmax + mem_read (one block per n) ----------------
__global__ __launch_bounds__(256)
void attn_memread(const __half* __restrict__ mv, const float* __restrict__ wq,
                  const float* __restrict__ gmask, __half* __restrict__ mem_read)
{
    int n = blockIdx.x;
    __shared__ __align__(16) __half smv[TT][1032];
    __shared__ float sw[HH][TT];
    __shared__ float ssm[HH][TT];
    int tid = threadIdx.x;

    for (int t = 0; t < TT; t++) {
        const ushort4* src = (const ushort4*)(mv + ((size_t)t * NN + n) * MM);
        ((ushort4*)&smv[t][0])[tid] = src[tid];
    }
    __syncthreads();

    if (tid < 128) {
        int h = tid >> 4, t = tid & 15;
        const float* w = wq + h * MM;
        float acc = 0.f;
        for (int m = 0; m < MM; m += 2) {
            float2 v = __half22float2(*(const __half2*)&smv[t][m]);
            acc = fmaf(v.x, w[m], acc);
            acc = fmaf(v.y, w[m + 1], acc);
        }
        sw[h][t] = acc;
    }
    __syncthreads();
    if (tid < 8) {
        int h = tid;
        float mx = -1e30f;
        for (int t = 0; t < TT; t++) mx = fmaxf(mx, sw[h][t]);
        float s = 0.f;
        for (int t = 0; t < TT; t++) { float e = __expf(sw[h][t] - mx); ssm[h][t] = e; s += e; }
        float inv = 1.0f / s;
        for (int t = 0; t < TT; t++) ssm[h][t] *= inv;
    }
    __syncthreads();

    const float* gm = gmask + (size_t)n * MM;
    #pragma unroll
    for (int mm = 0; mm < 4; mm++) {
        int m = tid + mm * 256;
        int h = m >> 7;
        float acc = 0.f;
        #pragma unroll
        for (int t = 0; t < TT; t++) acc = fmaf(__half2float(smv[t][m]), ssm[h][t], acc);
        acc *= gm[m];
        mem_read[(size_t)n * MM + m] = __float2half(acc);
    }
}

// ---------------- LayerNorm + residual broadcast over T (one block per n) ----------------
__global__ __launch_bounds__(256)
void ln_add(const float* __restrict__ mem_out, const float* __restrict__ x,
            const float* __restrict__ gamma, const float* __restrict__ beta,
            const float* __restrict__ mmix, float* __restrict__ out)
{
    int n = blockIdx.x, tid = threadIdx.x;
    int lane = tid & 63, wave = tid >> 6;
    __shared__ float sred[10];
    float4 v = ((const float4*)(mem_out + (size_t)n * DD))[tid];
    float s  = v.x + v.y + v.z + v.w;
    float ss = v.x * v.x + v.y * v.y + v.z * v.z + v.w * v.w;
    #pragma unroll
    for (int o = 32; o > 0; o >>= 1) { s += __shfl_down(s, o, 64); ss += __shfl_down(ss, o, 64); }
    if (lane == 0) { sred[wave * 2] = s; sred[wave * 2 + 1] = ss; }
    __syncthreads();
    if (tid == 0) {
        float S = 0.f, SS = 0.f;
        for (int w = 0; w < 4; w++) { S += sred[w * 2]; SS += sred[w * 2 + 1]; }
        float mu = S * (1.0f / DD);
        float var = SS * (1.0f / DD) - mu * mu;
        sred[8] = mu;
        sred[9] = rsqrtf(var + 1e-5f);
    }
    __syncthreads();
    float mu = sred[8], rs = sred[9];
    float4 g = ((const float4*)gamma)[tid];
    float4 b = ((const float4*)beta)[tid];
    float4 nv;
    nv.x = (v.x - mu) * rs * g.x + b.x;
    nv.y = (v.y - mu) * rs * g.y + b.y;
    nv.z = (v.z - mu) * rs * g.z + b.z;
    nv.w = (v.w - mu) * rs * g.w + b.w;
    float mix = 1.0f / (1.0f + expf(-mmix[0]));
    for (int t = 0; t < TT; t++) {
        size_t off = ((size_t)t * NN + n) * DD;
        float4 xv = ((const float4*)(x + off))[tid];
        float4 o;
        o.x = xv.x + mix * nv.x;
        o.y = xv.y + mix * nv.y;
        o.z = xv.z + mix * nv.z;
        o.w = xv.w + mix * nv.w;
        ((float4*)(out + off))[tid] = o;
    }
}

__global__ void ws_sentinel(float* out) { out[0] = 12345.0f; }

extern "C" void kernel_launch(void* const* d_in, const int* in_sizes, int n_in,
                              void* d_out, int out_size, void* d_ws, size_t ws_size,
                              hipStream_t stream)
{
    const float* x     = (const float*)d_in[0];
    const float* Wto   = (const float*)d_in[1];
    const float* Wg    = (const float*)d_in[2];
    const float* Wrk   = (const float*)d_in[3];
    const float* Wfrom = (const float*)d_in[4];
    const float* q     = (const float*)d_in[5];
    const float* gthr  = (const float*)d_in[6];
    const float* gamma = (const float*)d_in[7];
    const float* beta  = (const float*)d_in[8];
    const float* mmix  = (const float*)d_in[9];
    float* out = (float*)d_out;

    char* w = (char*)d_ws;
    size_t off = 0;
    auto alloc = [&](size_t bytes) -> void* {
        void* p = w + off;
        off += (bytes + 255) & ~(size_t)255;
        return p;
    };
    __half* x_hi   = (__half*)alloc((size_t)ROWS * DD * 2);     // 64 MB (row-permuted)
    __half* x_lo   = (__half*)alloc((size_t)ROWS * DD * 2);     // 64 MB (row-permuted)
    __half* wc_hi  = (__half*)alloc((size_t)JJ * DD * 2);       // 4 MB
    __half* wc_lo  = (__half*)alloc((size_t)JJ * DD * 2);       // 4 MB
    __half* wf_hi  = (__half*)alloc((size_t)DD * MM * 2);       // 2 MB
    float*  wq     = (float*) alloc((size_t)HH * MM * 4);
    __half* mv     = (__half*)alloc((size_t)TT * NN * MM * 2);  // 64 MB
    float*  gmask  = (float*) alloc((size_t)NN * MM * 4);       // 8 MB
    __half* m_read = (__half*)alloc((size_t)NN * MM * 2);       // 4 MB
    float*  m_out  = (float*) alloc((size_t)NN * DD * 4);       // 8 MB

    if (off > ws_size) {
        ws_sentinel<<<1, 1, 0, stream>>>(out);
        return;
    }

    // allow 128 KiB dynamic LDS for gemm8p (deterministic, capture-safe)
    hipFuncSetAttribute((const void*)gemm8p, hipFuncAttributeMaxDynamicSharedMemorySize, 131072);

    // 1) packs
    pack_hilo_perm<<<ROWS * DD / 4 / 256, 256, 0, stream>>>(x, x_hi, x_lo);
    pack_hilo<<<(MM * DD / 4 + 255) / 256, 256, 0, stream>>>(Wto, wc_hi, wc_lo, MM * DD / 4);
    pack_hilo<<<(MM * DD / 4 + 255) / 256, 256, 0, stream>>>(Wg, wc_hi + (size_t)MM * DD, wc_lo + (size_t)MM * DD, MM * DD / 4);
    pack_hi<<<(DD * MM / 4 + 255) / 256, 256, 0, stream>>>(Wfrom, wf_hi, DD * MM / 4);
    compute_wq<<<dim3(4, 8), 256, 0, stream>>>(Wrk, q, wq);

    // 2) big 3-term f16 GEMM + fused LIF epilogue -> mv, gmask (no mi_gi)
    gemm8p<<<(ROWS / 256) * (JJ / 256), 512, 131072, stream>>>(x_hi, x_lo, wc_hi, wc_lo, mv, gmask, gthr);

    // 3) attention scores + softmax + gated mem_read
    attn_memread<<<NN, 256, 0, stream>>>(mv, wq, gmask, m_read);

    // 4) mem_out = mem_read @ W_from^T  (2048 x 1024, K=1024), single-term f16
    gemm_f16<1><<<(NN / 128) * (DD / 128), 256, 0, stream>>>(m_read, m_read, wf_hi, wf_hi, m_out, MM, DD, 3);

    // 5) LayerNorm + residual broadcast over T
    ln_add<<<NN, 256, 0, stream>>>(m_out, x, gamma, beta, mmix, out);
}